// Round 1
// baseline (16619.829 us; speedup 1.0000x reference)
//
#include <hip/hip_runtime.h>

// Sizes
#define B_   32
#define S_   64
#define T_   64
#define H_   1024
#define H2_  2048
#define E_   512
#define V_   32000
#define K3_  3072   // H + 2H : [s | ctx] concatenated K
#define BT_  2048   // B*T == B*S

typedef unsigned short u16;
typedef __attribute__((ext_vector_type(8))) short short8_t;  // 8 x bf16
typedef __attribute__((ext_vector_type(4))) float f32x4;

__device__ __forceinline__ u16 f2bf(float f) {
  unsigned x = __float_as_uint(f);
  unsigned r = (x + 0x7fffu + ((x >> 16) & 1u)) >> 16;  // RNE
  return (u16)r;
}
__device__ __forceinline__ float bf2f(u16 h) {
  return __uint_as_float(((unsigned)h) << 16);
}
__device__ __forceinline__ float frcp(float x) { return __builtin_amdgcn_rcpf(x); }
__device__ __forceinline__ float ftanh(float x) {
  float e = __expf(2.f * x);
  return 1.f - 2.f * frcp(e + 1.f);
}
__device__ __forceinline__ float fsigm(float x) {
  return frcp(1.f + __expf(-x));
}

// ---------------- prologue kernels ----------------

// x[(t*B+b)][e] = embed[target[b][t]][e]
__global__ void k_gather(float* __restrict__ x, const float* __restrict__ embed,
                         const int* __restrict__ tgt) {
  int bid = blockIdx.x;              // t*B + b
  int t = bid >> 5, b = bid & 31;
  int row = tgt[b * T_ + t];
  const float4* src = (const float4*)(embed + (size_t)row * E_);
  float4* dst = (float4*)(x + (size_t)bid * E_);
  dst[threadIdx.x] = src[threadIdx.x];   // 128 threads * float4 = 512
}

// combined per-column gate biases (all step-invariant terms folded into xg)
__global__ void k_biascomb(float* bcr, float* bc2o,
                           const float* bi, const float* bh, const float* bc,
                           const float* bi2, const float* bh2, const float* bc2i) {
  int j = blockIdx.x * 256 + threadIdx.x;
  if (j < H_) {
    bcr[j]  = bi[j]  + bh[j]  + bc[j];     // first H cols of the 2H gate (only ones used)
    bc2o[j] = bi2[j] + bh2[j] + bc2i[j];
  }
}

// float4 -> bf16x4 cast (enc_h)
__global__ void k_cast4(u16* __restrict__ dst, const float* __restrict__ src) {
  size_t i = (size_t)blockIdx.x * blockDim.x + threadIdx.x;
  float4 v = ((const float4*)src)[i];
  ushort4 u; u.x = f2bf(v.x); u.y = f2bf(v.y); u.z = f2bf(v.z); u.w = f2bf(v.w);
  ((ushort4*)dst)[i] = u;
}

// Wprev (1024x1024 row-major) -> bf16 transposed [col][k]
__global__ __launch_bounds__(256) void k_pack_wprev(u16* __restrict__ out,
                                                    const float* __restrict__ W) {
  __shared__ float ld[64][33];
  int kt = blockIdx.x >> 5, jt = blockIdx.x & 31;
  int k0 = kt * 64, j0 = jt * 32;
  int t = threadIdx.x;
  #pragma unroll
  for (int i = 0; i < 8; ++i) {
    int idx = i * 256 + t; int kr = idx >> 5, jc = idx & 31;
    ld[kr][jc] = W[(size_t)(k0 + kr) * H_ + j0 + jc];
  }
  __syncthreads();
  #pragma unroll
  for (int i = 0; i < 8; ++i) {
    int idx = i * 256 + t; int pr = idx >> 6, kk = idx & 63;
    out[(size_t)(j0 + pr) * H_ + k0 + kk] = f2bf(ld[kk][pr]);
  }
}

// Pack gate weights: packed col p = 2*j + sel (sel 0: reset from Wh/Wc cols :H,
// sel 1: cand from Wh2/Wc2), K-vector = [Wh*[k][j] k<1024 ; Wc*[k-1024][j]].
// Split bf16: hi = bf16(v), lo = bf16(v - hi).
__global__ __launch_bounds__(256) void k_pack_wcat(
    u16* __restrict__ whi, u16* __restrict__ wlo,
    const float* __restrict__ Wh, const float* __restrict__ Wc,
    const float* __restrict__ Wh2, const float* __restrict__ Wc2) {
  __shared__ float ld[64][33];
  int sel = blockIdx.x & 1;
  int jt  = (blockIdx.x >> 1) & 31;
  int kt  = blockIdx.x >> 6;          // 0..47
  int k0 = kt * 64, j0 = jt * 32;
  int t = threadIdx.x;
  const float* srcW = (k0 < H_) ? (sel ? Wh2 : Wh) : (sel ? Wc2 : Wc);
  int ldw = sel ? H_ : H2_;
  int koff = (k0 < H_) ? k0 : (k0 - H_);
  #pragma unroll
  for (int i = 0; i < 8; ++i) {
    int idx = i * 256 + t; int kr = idx >> 5, jc = idx & 31;
    ld[kr][jc] = srcW[(size_t)(koff + kr) * ldw + j0 + jc];
  }
  __syncthreads();
  #pragma unroll
  for (int i = 0; i < 8; ++i) {
    int idx = i * 256 + t; int pr = idx >> 6, kk = idx & 63;
    float v = ld[kk][pr];
    u16 h = f2bf(v);
    size_t addr = (size_t)(2 * (j0 + pr) + sel) * K3_ + k0 + kk;
    whi[addr] = h;
    wlo[addr] = f2bf(v - bf2f(h));
  }
}

// ---------------- generic 128x128 bf16-MFMA GEMM (fp32 in, fp32/bf16 out) ----------------
// C[M x N] = A[M x K] @ B[K x N] + bias ;  M = mtiles*128, N = ntiles*128, K % 64 == 0
__global__ __launch_bounds__(256) void k_gemm(
    const float* __restrict__ A, int lda,
    const float* __restrict__ Bm, int ldb,
    void* __restrict__ Cv, int ldc, int outBf16,
    const float* __restrict__ bias,
    int mtiles, int ntiles, int K) {
  __shared__ u16 As[128][72];  // +8 pad -> 2-way bank alias only
  __shared__ u16 Bs[128][72];  // stored [n][k]
  int nwg = mtiles * ntiles;
  int bid = blockIdx.x;
  int cpx = nwg >> 3;                       // grid % 8 == 0 for all call sites
  int lb = (bid & 7) * cpx + (bid >> 3);    // XCD-contiguous chunks
  int ntb = lb / mtiles, mtb = lb - ntb * mtiles;   // M-major: B-panel L2 reuse
  size_t m0 = (size_t)mtb * 128, n0 = (size_t)ntb * 128;
  int t = threadIdx.x, lane = t & 63, wid = t >> 6;
  int wr = (wid >> 1) * 64, wc = (wid & 1) * 64;
  f32x4 acc[4][4] = {};
  for (int k0 = 0; k0 < K; k0 += 64) {
    #pragma unroll
    for (int i = 0; i < 8; ++i) {            // stage A: 128x64 fp32 -> bf16
      int f4 = i * 256 + t;
      int row = f4 >> 4, c4 = (f4 & 15) << 2;
      float4 v = *(const float4*)(A + (m0 + row) * (size_t)lda + k0 + c4);
      ushort4 u; u.x = f2bf(v.x); u.y = f2bf(v.y); u.z = f2bf(v.z); u.w = f2bf(v.w);
      *(ushort4*)&As[row][c4] = u;
    }
    #pragma unroll
    for (int i = 0; i < 8; ++i) {            // stage B transposed: [n][k]
      int f4 = i * 256 + t;
      int kr = f4 >> 5, c4 = (f4 & 31) << 2;
      float4 v = *(const float4*)(Bm + (size_t)(k0 + kr) * ldb + n0 + c4);
      Bs[c4 + 0][kr] = f2bf(v.x);
      Bs[c4 + 1][kr] = f2bf(v.y);
      Bs[c4 + 2][kr] = f2bf(v.z);
      Bs[c4 + 3][kr] = f2bf(v.w);
    }
    __syncthreads();
    #pragma unroll
    for (int kk = 0; kk < 64; kk += 32) {
      int ko = kk + (lane >> 4) * 8;
      short8_t am[4], bn[4];
      #pragma unroll
      for (int m = 0; m < 4; ++m) am[m] = *(const short8_t*)&As[wr + m * 16 + (lane & 15)][ko];
      #pragma unroll
      for (int n = 0; n < 4; ++n) bn[n] = *(const short8_t*)&Bs[wc + n * 16 + (lane & 15)][ko];
      #pragma unroll
      for (int m = 0; m < 4; ++m)
        #pragma unroll
        for (int n = 0; n < 4; ++n)
          acc[m][n] = __builtin_amdgcn_mfma_f32_16x16x32_bf16(am[m], bn[n], acc[m][n], 0, 0, 0);
    }
    __syncthreads();
  }
  #pragma unroll
  for (int n = 0; n < 4; ++n) {
    int col = wc + n * 16 + (lane & 15);
    float bv = bias ? bias[n0 + col] : 0.f;
    #pragma unroll
    for (int m = 0; m < 4; ++m) {
      size_t row = m0 + wr + m * 16 + ((lane >> 4) << 2);
      #pragma unroll
      for (int r = 0; r < 4; ++r) {
        float val = acc[m][n][r] + bv;
        if (outBf16) ((u16*)Cv)[(row + r) * (size_t)ldc + n0 + col] = f2bf(val);
        else ((float*)Cv)[(row + r) * (size_t)ldc + n0 + col] = val;
      }
    }
  }
}

// ---------------- per-step kernels ----------------

// q = s @ Wprev + bprev   (M=32, N=1024, K=1024; Wprev_t pre-packed bf16 [col][k])
__global__ __launch_bounds__(256) void k_q(
    float* __restrict__ q, const float* __restrict__ scur,
    const u16* __restrict__ wpt, const float* __restrict__ bprev) {
  __shared__ u16 As[32][72];
  __shared__ u16 Bs[64][72];
  int t = threadIdx.x, lane = t & 63, w = t >> 6;
  int c0 = blockIdx.x * 64;
  f32x4 acc[2] = {};
  for (int k0 = 0; k0 < H_; k0 += 64) {
    #pragma unroll
    for (int i = 0; i < 8; ++i) {
      int idx = i * 256 + t; int r = idx >> 6, kk = idx & 63;
      As[r][kk] = f2bf(scur[r * H_ + k0 + kk]);
    }
    #pragma unroll
    for (int i = 0; i < 4; ++i) {
      int idx = i * 256 + t; int c = idx >> 4, k4 = (idx & 15) << 2;
      *(ushort4*)&Bs[c][k4] = *(const ushort4*)(wpt + (size_t)(c0 + c) * H_ + k0 + k4);
    }
    __syncthreads();
    #pragma unroll
    for (int kk = 0; kk < 64; kk += 32) {
      int ko = kk + (lane >> 4) * 8;
      short8_t a0 = *(const short8_t*)&As[(lane & 15)][ko];
      short8_t a1 = *(const short8_t*)&As[16 + (lane & 15)][ko];
      short8_t b  = *(const short8_t*)&Bs[w * 16 + (lane & 15)][ko];
      acc[0] = __builtin_amdgcn_mfma_f32_16x16x32_bf16(a0, b, acc[0], 0, 0, 0);
      acc[1] = __builtin_amdgcn_mfma_f32_16x16x32_bf16(a1, b, acc[1], 0, 0, 0);
    }
    __syncthreads();
  }
  int col = c0 + w * 16 + (lane & 15);
  float bv = bprev[col];
  #pragma unroll
  for (int m = 0; m < 2; ++m) {
    int rbase = m * 16 + ((lane >> 4) << 2);
    #pragma unroll
    for (int r = 0; r < 4; ++r)
      q[(rbase + r) * H_ + col] = acc[m][r] + bv;
  }
}

// attention for one batch item: scores -> softmax -> ctx
__global__ __launch_bounds__(256) void k_attn(
    float* __restrict__ ctx, const float* __restrict__ q,
    const u16* __restrict__ encp, const u16* __restrict__ enchb,
    const float* __restrict__ wlin) {
  __shared__ float ql[H_];
  __shared__ float wl[H_];
  __shared__ float sc[64];
  int b = blockIdx.x, t = threadIdx.x;
  for (int i = t; i < H_; i += 256) { ql[i] = q[b * H_ + i]; wl[i] = wlin[i]; }
  __syncthreads();
  int w = t >> 6, lane = t & 63;
  for (int si = w; si < 64; si += 4) {
    const u16* ep = encp + (size_t)(b * 64 + si) * H_;
    float p = 0.f;
    for (int j = lane; j < H_; j += 64)
      p += ftanh(bf2f(ep[j]) + ql[j]) * wl[j];
    #pragma unroll
    for (int off = 32; off; off >>= 1) p += __shfl_xor(p, off, 64);
    if (lane == 0) sc[si] = p;     // att_blin: softmax-shift-invariant, skipped
  }
  __syncthreads();
  if (t < 64) {
    float v = sc[t];
    float m = v;
    #pragma unroll
    for (int off = 32; off; off >>= 1) m = fmaxf(m, __shfl_xor(m, off, 64));
    float e = __expf(v - m);
    float s = e;
    #pragma unroll
    for (int off = 32; off; off >>= 1) s += __shfl_xor(s, off, 64);
    sc[t] = e * frcp(s);
  }
  __syncthreads();
  for (int e0 = t; e0 < H2_; e0 += 256) {
    float a = 0.f;
    const u16* eh = enchb + (size_t)b * 64 * H2_ + e0;
    #pragma unroll 8
    for (int si = 0; si < 64; ++si)
      a += sc[si] * bf2f(eh[(size_t)si * H2_]);
    ctx[b * H2_ + e0] = a;
  }
}

// gates: [reset|cand] = [s|ctx] @ Wcat (split-bf16, 3 products) + xg ; s_new update
__global__ __launch_bounds__(256) void k_gates(
    float* __restrict__ snext, float* __restrict__ dech, float* __restrict__ fout,
    const float* __restrict__ scur, const float* __restrict__ ctx,
    const u16* __restrict__ whi, const u16* __restrict__ wlo,
    const float* __restrict__ xgr, const float* __restrict__ xg2,
    int tstep) {
  __shared__ u16 Ah[32][72], Al[32][72];
  __shared__ u16 Bh[64][72], Bl[64][72];
  int t = threadIdx.x, lane = t & 63, w = t >> 6;
  int c0 = blockIdx.x * 64;         // packed cols (interleaved reset/cand)
  f32x4 acc[2] = {};
  for (int k0 = 0; k0 < K3_; k0 += 64) {
    #pragma unroll
    for (int i = 0; i < 8; ++i) {
      int idx = i * 256 + t; int r = idx >> 6, kk = idx & 63;
      int kg = k0 + kk;
      float v = (kg < H_) ? scur[r * H_ + kg] : ctx[r * H2_ + kg - H_];
      u16 h = f2bf(v);
      Ah[r][kk] = h;
      Al[r][kk] = f2bf(v - bf2f(h));
    }
    #pragma unroll
    for (int i = 0; i < 4; ++i) {
      int idx = i * 256 + t; int c = idx >> 4, k4 = (idx & 15) << 2;
      size_t off = (size_t)(c0 + c) * K3_ + k0 + k4;
      *(ushort4*)&Bh[c][k4] = *(const ushort4*)(whi + off);
      *(ushort4*)&Bl[c][k4] = *(const ushort4*)(wlo + off);
    }
    __syncthreads();
    #pragma unroll
    for (int kk = 0; kk < 64; kk += 32) {
      int ko = kk + (lane >> 4) * 8;
      short8_t a0h = *(const short8_t*)&Ah[(lane & 15)][ko];
      short8_t a1h = *(const short8_t*)&Ah[16 + (lane & 15)][ko];
      short8_t a0l = *(const short8_t*)&Al[(lane & 15)][ko];
      short8_t a1l = *(const short8_t*)&Al[16 + (lane & 15)][ko];
      short8_t bh  = *(const short8_t*)&Bh[w * 16 + (lane & 15)][ko];
      short8_t bl  = *(const short8_t*)&Bl[w * 16 + (lane & 15)][ko];
      acc[0] = __builtin_amdgcn_mfma_f32_16x16x32_bf16(a0h, bh, acc[0], 0, 0, 0);
      acc[0] = __builtin_amdgcn_mfma_f32_16x16x32_bf16(a0h, bl, acc[0], 0, 0, 0);
      acc[0] = __builtin_amdgcn_mfma_f32_16x16x32_bf16(a0l, bh, acc[0], 0, 0, 0);
      acc[1] = __builtin_amdgcn_mfma_f32_16x16x32_bf16(a1h, bh, acc[1], 0, 0, 0);
      acc[1] = __builtin_amdgcn_mfma_f32_16x16x32_bf16(a1h, bl, acc[1], 0, 0, 0);
      acc[1] = __builtin_amdgcn_mfma_f32_16x16x32_bf16(a1l, bh, acc[1], 0, 0, 0);
    }
    __syncthreads();
  }
  int colp = c0 + w * 16 + (lane & 15);
  int j = colp >> 1;
  int isc = colp & 1;               // 0: reset pre-act, 1: cand pre-act
  #pragma unroll
  for (int m = 0; m < 2; ++m) {
    int rbase = m * 16 + ((lane >> 4) << 2);
    #pragma unroll
    for (int r = 0; r < 4; ++r) {
      int row = rbase + r;
      float xv = isc ? xg2[(size_t)(tstep * B_ + row) * H_ + j]
                     : xgr[(size_t)(tstep * B_ + row) * H_ + j];
      float pre = acc[m][r] + xv;
      float part = __shfl_xor(pre, 1, 64);   // pair lanes: even=reset, odd=cand
      float rpre = isc ? part : pre;
      float cpre = isc ? pre : part;
      float reset = fsigm(rpre);
      float cand  = ftanh(cpre);
      float sp = scur[row * H_ + j];
      float sn = sp + reset * (cand - sp);
      if (!isc) {
        snext[row * H_ + j] = sn;
        dech[(size_t)(row * T_ + tstep) * H_ + j] = sn;   // [b][t][h]
        if (tstep == T_ - 1) fout[row * H_ + j] = sn;
      }
    }
  }
}

// ---------------- host ----------------

extern "C" void kernel_launch(void* const* d_in, const int* in_sizes, int n_in,
                              void* d_out, int out_size, void* d_ws, size_t ws_size,
                              hipStream_t stream) {
  const float* enc_h    = (const float*)d_in[0];
  const float* prev_s   = (const float*)d_in[1];
  const int*   target   = (const int*)d_in[2];
  const float* embed    = (const float*)d_in[3];
  const float* att_Wenc = (const float*)d_in[4];
  const float* att_benc = (const float*)d_in[5];
  const float* att_Wprev= (const float*)d_in[6];
  const float* att_bprev= (const float*)d_in[7];
  const float* att_wlin = (const float*)d_in[8];
  // d_in[9] att_blin: softmax-invariant constant, unused
  const float* dc_Wi    = (const float*)d_in[10];
  const float* dc_bi    = (const float*)d_in[11];
  const float* dc_Wh    = (const float*)d_in[12];
  const float* dc_bh    = (const float*)d_in[13];
  const float* dc_Wc    = (const float*)d_in[14];
  const float* dc_bc    = (const float*)d_in[15];
  const float* dc_Wi2   = (const float*)d_in[16];
  const float* dc_bi2   = (const float*)d_in[17];
  const float* dc_Wh2   = (const float*)d_in[18];
  const float* dc_bh2   = (const float*)d_in[19];
  const float* dc_Wc2   = (const float*)d_in[20];
  const float* dc_bc2   = (const float*)d_in[21];
  const float* out_W    = (const float*)d_in[22];
  const float* out_b    = (const float*)d_in[23];

  char* w = (char*)d_ws;
  float* x     = (float*)(w);                            // 4 MB
  float* xgr   = (float*)(w + (4u << 20));               // 8 MB
  float* xg2   = (float*)(w + (12u << 20));              // 8 MB
  float* dech  = (float*)(w + (20u << 20));              // 8 MB
  u16*   encp  = (u16*)  (w + (28u << 20));              // 4 MB (bf16)
  u16*   enchb = (u16*)  (w + (32u << 20));              // 8 MB (bf16)
  u16*   wpt   = (u16*)  (w + (40u << 20));              // 2 MB
  u16*   whi   = (u16*)  (w + (42u << 20));              // 12 MB
  u16*   wlo   = (u16*)  (w + (54u << 20));              // 12 MB
  float* q     = (float*)(w + (66u << 20));                        // 128 KB
  float* ctx   = (float*)(w + (66u << 20) + (128u << 10));         // 256 KB
  float* s0    = (float*)(w + (66u << 20) + (384u << 10));         // 128 KB
  float* s1    = (float*)(w + (66u << 20) + (512u << 10));         // 128 KB
  float* bcr   = (float*)(w + (66u << 20) + (640u << 10));         // 4 KB
  float* bc2   = (float*)(w + (66u << 20) + (644u << 10));         // 4 KB
  float* fout  = (float*)d_out + (size_t)BT_ * V_;       // final_s tail of d_out

  // prologue (step-invariant)
  k_gather  <<<BT_, 128, 0, stream>>>(x, embed, target);
  k_biascomb<<<4, 256, 0, stream>>>(bcr, bc2, dc_bi, dc_bh, dc_bc, dc_bi2, dc_bh2, dc_bc2);
  k_cast4   <<<4096, 256, 0, stream>>>(enchb, enc_h);            // 4,194,304 elems
  k_pack_wprev<<<512, 256, 0, stream>>>(wpt, att_Wprev);
  k_pack_wcat <<<3072, 256, 0, stream>>>(whi, wlo, dc_Wh, dc_Wc, dc_Wh2, dc_Wc2);
  // enc_proj (bf16 out), x@Wi terms (fp32 out, only first H gate cols needed)
  k_gemm<<<16 * 8, 256, 0, stream>>>(enc_h, H2_, att_Wenc, H_, encp, H_, 1, att_benc, 16, 8, H2_);
  k_gemm<<<16 * 8, 256, 0, stream>>>(x, E_, dc_Wi,  H2_, xgr, H_, 0, bcr, 16, 8, E_);
  k_gemm<<<16 * 8, 256, 0, stream>>>(x, E_, dc_Wi2, H_,  xg2, H_, 0, bc2, 16, 8, E_);
  hipMemcpyAsync(s0, prev_s, (size_t)B_ * H_ * sizeof(float), hipMemcpyDeviceToDevice, stream);

  // sequential decode
  for (int t = 0; t < T_; ++t) {
    float* scur  = (t & 1) ? s1 : s0;
    float* snext = (t & 1) ? s0 : s1;
    k_q    <<<16, 256, 0, stream>>>(q, scur, wpt, att_bprev);
    k_attn <<<32, 256, 0, stream>>>(ctx, q, encp, enchb, att_wlin);
    k_gates<<<32, 256, 0, stream>>>(snext, dech, fout, scur, ctx, whi, wlo, xgr, xg2, t);
  }

  // vocab projection: (2048 x 1024) @ (1024 x 32000) + out_b
  k_gemm<<<16 * 250, 256, 0, stream>>>(dech, H_, out_W, V_, d_out, V_, 0, out_b, 16, 250, H_);
}

// Round 2
// 7642.388 us; speedup vs baseline: 2.1747x; 2.1747x over previous
//
#include <hip/hip_runtime.h>

// Sizes
#define B_   32
#define S_   64
#define T_   64
#define H_   1024
#define H2_  2048
#define E_   512
#define V_   32000
#define K3_  3072
#define BT_  2048

typedef unsigned short u16;
typedef __attribute__((ext_vector_type(8))) short short8_t;  // 8 x bf16
typedef __attribute__((ext_vector_type(4))) float f32x4;

__device__ __forceinline__ u16 f2bf(float f) {
  unsigned x = __float_as_uint(f);
  unsigned r = (x + 0x7fffu + ((x >> 16) & 1u)) >> 16;  // RNE
  return (u16)r;
}
__device__ __forceinline__ float bf2f(u16 h) {
  return __uint_as_float(((unsigned)h) << 16);
}
__device__ __forceinline__ float frcp(float x) { return __builtin_amdgcn_rcpf(x); }
__device__ __forceinline__ float ftanh(float x) {
  float e = __expf(2.f * x);
  return 1.f - 2.f * frcp(e + 1.f);
}
__device__ __forceinline__ float fsigm(float x) {
  return frcp(1.f + __expf(-x));
}

// ---------------- workspace layout (bytes) ----------------
#define MB_ (1ull << 20)
#define KB_ (1ull << 10)
// pool [0, 54MB): dead after mega; wot (32MB/half) aliases [0,32MB)
#define X_OFF    (0)              // 4MB; encp aliases this after xgr/xg2 gemms
#define XGR_OFF  (4*MB_)          // 8MB
#define XG2_OFF  (12*MB_)         // 8MB
#define ENCT_OFF (20*MB_)         // 8MB
#define WQF_OFF  (28*MB_)         // 2MB
#define WGF_OFF  (30*MB_)         // 24MB
#define WOT_OFF  (0)              // 32MB (after mega only)
#define DECH_OFF (54*MB_)         // 4MB
#define SF_OFF   (58*MB_)         // 2 x 128KB
#define SH_OFF   (58*MB_ + 256*KB_)   // 2 x 64KB
#define SL_OFF   (58*MB_ + 384*KB_)   // 2 x 64KB
#define QP_OFF   (58*MB_ + 512*KB_)   // 512KB
#define CH_OFF   (58*MB_ + 1024*KB_)  // 128KB
#define CL_OFF   (58*MB_ + 1152*KB_)  // 128KB
#define SC_OFF   (58*MB_ + 1280*KB_)  // 8KB
#define BCR_OFF  (58*MB_ + 1288*KB_)  // 4KB
#define BC2_OFF  (58*MB_ + 1292*KB_)  // 4KB
#define BAR_OFF  (58*MB_ + 1296*KB_)  // 4KB

// ---------------- prologue kernels ----------------

__global__ void k_gather(float* __restrict__ x, const float* __restrict__ embed,
                         const int* __restrict__ tgt) {
  int bid = blockIdx.x;              // t*B + b
  int t = bid >> 5, b = bid & 31;
  int row = tgt[b * T_ + t];
  const float4* src = (const float4*)(embed + (size_t)row * E_);
  float4* dst = (float4*)(x + (size_t)bid * E_);
  dst[threadIdx.x] = src[threadIdx.x];
}

__global__ void k_biascomb(float* bcr, float* bc2o,
                           const float* bi, const float* bh, const float* bc,
                           const float* bi2, const float* bh2, const float* bc2i) {
  int j = blockIdx.x * 256 + threadIdx.x;
  if (j < H_) {
    bcr[j]  = bi[j]  + bh[j]  + bc[j];
    bc2o[j] = bi2[j] + bh2[j] + bc2i[j];
  }
}

// generic 128x128 bf16-MFMA GEMM (fp32 in, fp32/bf16 out) — prologue only
__global__ __launch_bounds__(256) void k_gemm(
    const float* __restrict__ A, int lda,
    const float* __restrict__ Bm, int ldb,
    void* __restrict__ Cv, int ldc, int outBf16,
    const float* __restrict__ bias,
    int mtiles, int ntiles, int K) {
  __shared__ u16 As[128][72];
  __shared__ u16 Bs[128][72];
  int nwg = mtiles * ntiles;
  int bid = blockIdx.x;
  int cpx = nwg >> 3;
  int lb = (bid & 7) * cpx + (bid >> 3);
  int ntb = lb / mtiles, mtb = lb - ntb * mtiles;
  size_t m0 = (size_t)mtb * 128, n0 = (size_t)ntb * 128;
  int t = threadIdx.x, lane = t & 63, wid = t >> 6;
  int wr = (wid >> 1) * 64, wc = (wid & 1) * 64;
  f32x4 acc[4][4] = {};
  for (int k0 = 0; k0 < K; k0 += 64) {
    #pragma unroll
    for (int i = 0; i < 8; ++i) {
      int f4 = i * 256 + t;
      int row = f4 >> 4, c4 = (f4 & 15) << 2;
      float4 v = *(const float4*)(A + (m0 + row) * (size_t)lda + k0 + c4);
      ushort4 u; u.x = f2bf(v.x); u.y = f2bf(v.y); u.z = f2bf(v.z); u.w = f2bf(v.w);
      *(ushort4*)&As[row][c4] = u;
    }
    #pragma unroll
    for (int i = 0; i < 8; ++i) {
      int f4 = i * 256 + t;
      int kr = f4 >> 5, c4 = (f4 & 31) << 2;
      float4 v = *(const float4*)(Bm + (size_t)(k0 + kr) * ldb + n0 + c4);
      Bs[c4 + 0][kr] = f2bf(v.x);
      Bs[c4 + 1][kr] = f2bf(v.y);
      Bs[c4 + 2][kr] = f2bf(v.z);
      Bs[c4 + 3][kr] = f2bf(v.w);
    }
    __syncthreads();
    #pragma unroll
    for (int kk = 0; kk < 64; kk += 32) {
      int ko = kk + (lane >> 4) * 8;
      short8_t am[4], bn[4];
      #pragma unroll
      for (int m = 0; m < 4; ++m) am[m] = *(const short8_t*)&As[wr + m * 16 + (lane & 15)][ko];
      #pragma unroll
      for (int n = 0; n < 4; ++n) bn[n] = *(const short8_t*)&Bs[wc + n * 16 + (lane & 15)][ko];
      #pragma unroll
      for (int m = 0; m < 4; ++m)
        #pragma unroll
        for (int n = 0; n < 4; ++n)
          acc[m][n] = __builtin_amdgcn_mfma_f32_16x16x32_bf16(am[m], bn[n], acc[m][n], 0, 0, 0);
    }
    __syncthreads();
  }
  #pragma unroll
  for (int n = 0; n < 4; ++n) {
    int col = wc + n * 16 + (lane & 15);
    float bv = bias ? bias[n0 + col] : 0.f;
    #pragma unroll
    for (int m = 0; m < 4; ++m) {
      size_t row = m0 + wr + m * 16 + ((lane >> 4) << 2);
      #pragma unroll
      for (int r = 0; r < 4; ++r) {
        float val = acc[m][n][r] + bv;
        if (outBf16) ((u16*)Cv)[(row + r) * (size_t)ldc + n0 + col] = f2bf(val);
        else ((float*)Cv)[(row + r) * (size_t)ldc + n0 + col] = val;
      }
    }
  }
}

// enc_h -> encT[e][b][si] bf16 (transposed for ctx dot)
__global__ __launch_bounds__(256) void k_transE(u16* __restrict__ encT,
                                                const float* __restrict__ enc_h) {
  __shared__ u16 ld[64][68];
  int b = blockIdx.x >> 5, et = blockIdx.x & 31;
  int e0 = et * 64;
  int t = threadIdx.x;
  #pragma unroll
  for (int i = 0; i < 4; ++i) {
    int f4 = i * 256 + t;
    int si = f4 >> 4, e4 = (f4 & 15) << 2;
    float4 v = *(const float4*)(enc_h + ((size_t)(b * 64 + si)) * H2_ + e0 + e4);
    ld[si][e4 + 0] = f2bf(v.x); ld[si][e4 + 1] = f2bf(v.y);
    ld[si][e4 + 2] = f2bf(v.z); ld[si][e4 + 3] = f2bf(v.w);
  }
  __syncthreads();
  #pragma unroll
  for (int i = 0; i < 2; ++i) {
    int idx = i * 256 + t;
    int e = idx >> 3, s8 = (idx & 7) << 3;
    short8_t o;
    #pragma unroll
    for (int k = 0; k < 8; ++k) o[k] = (short)ld[s8 + k][e];
    *(short8_t*)(encT + ((size_t)(e0 + e)) * 2048 + b * 64 + s8) = o;
  }
}

// att_Wprev -> wqf frag-major bf16: [g 64][kb 32][sub 4][c 16][j 8]
__global__ __launch_bounds__(256) void k_packq(u16* __restrict__ wqf,
                                               const float* __restrict__ W) {
  int lin = blockIdx.x * 256 + threadIdx.x;   // 131072
  int c = lin & 15, sub = (lin >> 4) & 3, kb = (lin >> 6) & 31, g = lin >> 11;
  int col = g * 16 + c, kbase = kb * 32 + sub * 8;
  short8_t o;
  #pragma unroll
  for (int j = 0; j < 8; ++j) o[j] = (short)f2bf(W[(size_t)(kbase + j) * H_ + col]);
  *(short8_t*)(wqf + (size_t)lin * 8) = o;
}

// gate weights -> wgf frag-major: [g 256][kb 96][sub 4][c 16][j 8]
// c<8: hi of pcol g*8+c ; c>=8: lo of pcol g*8+c-8 ; pcol = 2*jj+sel
__global__ __launch_bounds__(256) void k_packg(
    u16* __restrict__ wgf, const float* __restrict__ Wh, const float* __restrict__ Wc,
    const float* __restrict__ Wh2, const float* __restrict__ Wc2) {
  size_t lin = (size_t)blockIdx.x * 256 + threadIdx.x;   // 1,572,864
  int c = (int)(lin & 15), sub = (int)((lin >> 4) & 3);
  int x = (int)(lin >> 6);
  int kb = x % 96, g = x / 96;
  int cc = c & 7, islo = c >> 3;
  int p = g * 8 + cc, jj = p >> 1, sel = p & 1;
  int kbase = kb * 32 + sub * 8;
  short8_t o;
  #pragma unroll
  for (int j = 0; j < 8; ++j) {
    int k = kbase + j;
    float v;
    if (k < H_) v = sel ? Wh2[(size_t)k * H_ + jj] : Wh[(size_t)k * H2_ + jj];
    else { int km = k - H_; v = sel ? Wc2[(size_t)km * H_ + jj] : Wc[(size_t)km * H2_ + jj]; }
    u16 h = f2bf(v);
    o[j] = (short)(islo ? f2bf(v - bf2f(h)) : h);
  }
  *(short8_t*)(wgf + lin * 8) = o;
}

// out_W half -> wot bf16 [nLocal 16000][k 1024]
__global__ __launch_bounds__(256) void k_wtrans(u16* __restrict__ wot,
                                                const float* __restrict__ W, int nbase) {
  __shared__ u16 ld[64][68];
  int nt = blockIdx.x % 250, kt = blockIdx.x / 250;
  int n0 = nbase + nt * 64, k0 = kt * 64;
  int t = threadIdx.x;
  #pragma unroll
  for (int i = 0; i < 4; ++i) {
    int f4 = i * 256 + t;
    int kr = f4 >> 4, n4 = (f4 & 15) << 2;
    float4 v = *(const float4*)(W + (size_t)(k0 + kr) * V_ + n0 + n4);
    ld[kr][n4 + 0] = f2bf(v.x); ld[kr][n4 + 1] = f2bf(v.y);
    ld[kr][n4 + 2] = f2bf(v.z); ld[kr][n4 + 3] = f2bf(v.w);
  }
  __syncthreads();
  #pragma unroll
  for (int i = 0; i < 2; ++i) {
    int idx = i * 256 + t;
    int n = idx >> 3, k8 = (idx & 7) << 3;
    short8_t o;
    #pragma unroll
    for (int k = 0; k < 8; ++k) o[k] = (short)ld[k8 + k][n];
    *(short8_t*)(wot + ((size_t)(nt * 64 + n)) * H_ + k0 + k8) = o;
  }
}

// final GEMM: dech bf16 [2048][1024] @ wot^T -> C fp32 (per 16000-col half)
__global__ __launch_bounds__(256) void k_gemm2(
    const u16* __restrict__ A, const u16* __restrict__ Bt,
    float* __restrict__ C, const float* __restrict__ bias, int n0g) {
  __shared__ u16 As[128][72];
  __shared__ u16 Bs[128][72];
  int bid = blockIdx.x;
  int lb = (bid & 7) * 250 + (bid >> 3);   // 2000 blocks, XCD-chunked
  int mtb = lb & 15, ntb = lb >> 4;
  size_t m0 = (size_t)mtb * 128;
  size_t nl0 = (size_t)ntb * 128;
  int t = threadIdx.x, lane = t & 63, wid = t >> 6;
  int wr = (wid >> 1) * 64, wc = (wid & 1) * 64;
  f32x4 acc[4][4] = {};
  for (int k0 = 0; k0 < H_; k0 += 64) {
    #pragma unroll
    for (int i = 0; i < 4; ++i) {
      int idx = i * 256 + t;
      int row = idx >> 3, c8 = (idx & 7) << 3;
      *(short8_t*)&As[row][c8] = *(const short8_t*)(A + (m0 + row) * H_ + k0 + c8);
      *(short8_t*)&Bs[row][c8] = *(const short8_t*)(Bt + (nl0 + row) * H_ + k0 + c8);
    }
    __syncthreads();
    #pragma unroll
    for (int kk = 0; kk < 64; kk += 32) {
      int ko = kk + (lane >> 4) * 8;
      short8_t am[4], bn[4];
      #pragma unroll
      for (int m = 0; m < 4; ++m) am[m] = *(const short8_t*)&As[wr + m * 16 + (lane & 15)][ko];
      #pragma unroll
      for (int n = 0; n < 4; ++n) bn[n] = *(const short8_t*)&Bs[wc + n * 16 + (lane & 15)][ko];
      #pragma unroll
      for (int m = 0; m < 4; ++m)
        #pragma unroll
        for (int n = 0; n < 4; ++n)
          acc[m][n] = __builtin_amdgcn_mfma_f32_16x16x32_bf16(am[m], bn[n], acc[m][n], 0, 0, 0);
    }
    __syncthreads();
  }
  #pragma unroll
  for (int n = 0; n < 4; ++n) {
    int col = n0g + (int)nl0 + wc + n * 16 + (lane & 15);
    float bv = bias[col];
    #pragma unroll
    for (int m = 0; m < 4; ++m) {
      size_t row = m0 + wr + m * 16 + ((lane >> 4) << 2);
      #pragma unroll
      for (int r = 0; r < 4; ++r)
        C[(row + r) * (size_t)V_ + col] = acc[m][n][r] + bv;
    }
  }
}

// ---------------- persistent decoder kernel ----------------

__device__ __forceinline__ void gridbar(int* bar, int target) {
  __syncthreads();
  if (threadIdx.x == 0) {
    int* leaf  = bar;                 // 32 x 16 ints
    int* root  = bar + 512;
    int* epoch = bar + 528;
    int li = (blockIdx.x >> 3) * 16;
    if (__hip_atomic_fetch_add(&leaf[li], 1, __ATOMIC_ACQ_REL, __HIP_MEMORY_SCOPE_AGENT) == 7) {
      __hip_atomic_store(&leaf[li], 0, __ATOMIC_RELAXED, __HIP_MEMORY_SCOPE_AGENT);
      if (__hip_atomic_fetch_add(root, 1, __ATOMIC_ACQ_REL, __HIP_MEMORY_SCOPE_AGENT) == 31) {
        __hip_atomic_store(root, 0, __ATOMIC_RELAXED, __HIP_MEMORY_SCOPE_AGENT);
        __hip_atomic_store(epoch, target, __ATOMIC_RELEASE, __HIP_MEMORY_SCOPE_AGENT);
      }
    }
    while (__hip_atomic_load(epoch, __ATOMIC_RELAXED, __HIP_MEMORY_SCOPE_AGENT) != target)
      __builtin_amdgcn_s_sleep(1);
    __threadfence();
  }
  __syncthreads();
}

__global__ __launch_bounds__(512) void k_mega(
    float* __restrict__ sF, u16* __restrict__ sh, u16* __restrict__ sl,
    float* __restrict__ qp, u16* __restrict__ ch, u16* __restrict__ cl,
    float* __restrict__ scores, u16* __restrict__ dech, float* __restrict__ fout,
    const u16* __restrict__ wqf, const u16* __restrict__ wgf,
    const u16* __restrict__ encp, const u16* __restrict__ encT,
    const float* __restrict__ xgr, const float* __restrict__ xg2,
    const float* __restrict__ prev_s, const float* __restrict__ att_bprev,
    const float* __restrict__ att_wlin, int* bar) {
  const int t = threadIdx.x, blk = blockIdx.x;
  const int lane = t & 63, wid = t >> 6;
  __shared__ char smem_raw[8192];
  int ep = 0;

  // P0: init state buffers from prev_s
  {
    int idx = blk * 512 + t;
    if (idx < B_ * H_) {
      float v = prev_s[idx];
      sF[idx] = v;
      u16 h = f2bf(v);
      sh[idx] = h;
      sl[idx] = f2bf(v - bf2f(h));
    }
  }
  gridbar(bar, ++ep);

  for (int ts = 0; ts < T_; ++ts) {
    const int pb = ts & 1;
    const float* sFc = sF + pb * (B_ * H_);
    float*       sFn = sF + (pb ^ 1) * (B_ * H_);
    const u16*   shc = sh + pb * (B_ * H_);
    u16*         shn = sh + (pb ^ 1) * (B_ * H_);
    const u16*   slc = sl + pb * (B_ * H_);
    u16*         sln = sl + (pb ^ 1) * (B_ * H_);

    // ---- P1: q partials = s @ Wprev  (64 col-groups x 4 K-quarters) ----
    {
      int g = blk & 63, kq = blk >> 6;
      int mf = wid & 1, ks = wid >> 1;         // ks 0..3
      int row = (lane & 15) + mf * 16;
      int klo = (lane >> 4) * 8;
      f32x4 acc = {};
      #pragma unroll
      for (int kk = 0; kk < 2; ++kk) {
        int kb = kq * 8 + ks * 2 + kk;
        short8_t av = *(const short8_t*)(shc + row * H_ + kb * 32 + klo);
        short8_t bv = *(const short8_t*)(wqf + ((size_t)g * 32 + kb) * 512 + lane * 8);
        acc = __builtin_amdgcn_mfma_f32_16x16x32_bf16(av, bv, acc, 0, 0, 0);
      }
      f32x4* scr = (f32x4*)smem_raw;
      if (ks > 0) scr[((ks - 1) * 2 + mf) * 64 + lane] = acc;
      __syncthreads();
      if (wid < 2) {
        #pragma unroll
        for (int i = 0; i < 3; ++i) acc += scr[(i * 2 + wid) * 64 + lane];
        int col = g * 16 + (lane & 15);
        int rb = wid * 16 + (lane >> 4) * 4;
        #pragma unroll
        for (int r = 0; r < 4; ++r)
          qp[((size_t)(kq * 32) + rb + r) * H_ + col] = acc[r];
      }
    }
    gridbar(bar, ++ep);

    // ---- P2: scores (8 blocks per b, 1 wave per si) ----
    {
      int b = blk >> 3, si0 = (blk & 7) * 8;
      float* qL = (float*)smem_raw;        // 1024
      float* wlL = qL + 1024;              // 1024
      for (int idx = t; idx < H_; idx += 512) {
        float v = att_bprev[idx];
        #pragma unroll
        for (int kq = 0; kq < 4; ++kq) v += qp[((size_t)kq * 32 + b) * H_ + idx];
        qL[idx] = v;
        wlL[idx] = att_wlin[idx];
      }
      __syncthreads();
      const u16* eprow = encp + ((size_t)(b * 64 + si0 + wid)) * H_;
      float p = 0.f;
      #pragma unroll
      for (int jj = 0; jj < 16; ++jj) {
        int j = lane + 64 * jj;
        p += ftanh(bf2f(eprow[j]) + qL[j]) * wlL[j];
      }
      #pragma unroll
      for (int off = 32; off; off >>= 1) p += __shfl_xor(p, off, 64);
      if (lane == 0) scores[b * 64 + si0 + wid] = p;
    }
    gridbar(bar, ++ep);

    // ---- P3: softmax (redundant per block) + ctx cols, split-bf16 out ----
    {
      float* sL = (float*)smem_raw;   // 2048
      for (int idx = t; idx < 2048; idx += 512) sL[idx] = scores[idx];
      __syncthreads();
      {
        int b = t >> 4, l16 = t & 15;
        float v[4];
        #pragma unroll
        for (int i = 0; i < 4; ++i) v[i] = sL[b * 64 + l16 * 4 + i];
        float m = fmaxf(fmaxf(v[0], v[1]), fmaxf(v[2], v[3]));
        #pragma unroll
        for (int off = 8; off; off >>= 1) m = fmaxf(m, __shfl_xor(m, off, 64));
        float e[4], s = 0.f;
        #pragma unroll
        for (int i = 0; i < 4; ++i) { e[i] = __expf(v[i] - m); s += e[i]; }
        #pragma unroll
        for (int off = 8; off; off >>= 1) s += __shfl_xor(s, off, 64);
        float inv = frcp(s);
        #pragma unroll
        for (int i = 0; i < 4; ++i) sL[b * 64 + l16 * 4 + i] = e[i] * inv;
      }
      __syncthreads();
      int out = t >> 1, half = t & 1;
      int b = out >> 3, ec = out & 7;
      int ecg = blk * 8 + ec;
      const u16* ebase = encT + (size_t)ecg * 2048 + b * 64 + half * 32;
      const float* abase = sL + b * 64 + half * 32;
      float a = 0.f;
      #pragma unroll
      for (int i = 0; i < 32; ++i) a += abase[i] * bf2f(ebase[i]);
      a += __shfl_xor(a, 1, 64);
      if (half == 0) {
        u16 hh = f2bf(a);
        ch[b * H2_ + ecg] = hh;
        cl[b * H2_ + ecg] = f2bf(a - bf2f(hh));
      }
    }
    gridbar(bar, ++ep);

    // ---- P4: gates (8 packed cols per block) + state update ----
    {
      int mf = wid & 1, kq4 = wid >> 1;   // 4 K-quarters x 24 kb
      int row = (lane & 15) + mf * 16;
      int klo = (lane >> 4) * 8;
      const u16* bb = wgf + (size_t)blk * 49152 + lane * 8;
      f32x4 acc = {};
      for (int kb = kq4 * 24; kb < kq4 * 24 + 24; ++kb) {
        int k = kb * 32 + klo;
        const u16 *ah, *al;
        if (k < H_) { ah = shc + row * H_ + k;           al = slc + row * H_ + k; }
        else        { ah = ch + row * H2_ + (k - H_);    al = cl + row * H2_ + (k - H_); }
        short8_t av = *(const short8_t*)ah;
        short8_t lv = *(const short8_t*)al;
        short8_t bv = *(const short8_t*)(bb + (size_t)kb * 512);
        acc = __builtin_amdgcn_mfma_f32_16x16x32_bf16(av, bv, acc, 0, 0, 0);
        acc = __builtin_amdgcn_mfma_f32_16x16x32_bf16(lv, bv, acc, 0, 0, 0);
      }
      f32x4* scr = (f32x4*)smem_raw;
      if (kq4 > 0) scr[((kq4 - 1) * 2 + mf) * 64 + lane] = acc;
      __syncthreads();
      if (wid < 2) {
        #pragma unroll
        for (int i = 0; i < 3; ++i) acc += scr[(i * 2 + wid) * 64 + lane];
        float tot[4];
        #pragma unroll
        for (int r = 0; r < 4; ++r) tot[r] = acc[r] + __shfl_xor(acc[r], 8, 64);
        int c = lane & 15;
        if (c < 8) {
          int pc = blk * 8 + c;
          int j = pc >> 1, isc = pc & 1;
          int rb = wid * 16 + (lane >> 4) * 4;
          #pragma unroll
          for (int r = 0; r < 4; ++r) {
            int brow = rb + r;
            float xv = (isc ? xg2 : xgr)[((size_t)ts * 32 + brow) * H_ + j];
            float pre = tot[r] + xv;
            float mate = __shfl_xor(pre, 1, 64);
            float rpre = isc ? mate : pre;
            float cpre = isc ? pre : mate;
            float rg = fsigm(rpre);
            float cg = ftanh(cpre);
            float sp = sFc[brow * H_ + j];
            float sn = sp + rg * (cg - sp);
            if (!isc) {
              sFn[brow * H_ + j] = sn;
              u16 hh = f2bf(sn);
              shn[brow * H_ + j] = hh;
              sln[brow * H_ + j] = f2bf(sn - bf2f(hh));
              dech[((size_t)brow * 64 + ts) * H_ + j] = hh;
              if (ts == T_ - 1) fout[brow * H_ + j] = sn;
            }
          }
        }
      }
    }
    gridbar(bar, ++ep);
  }
}

// ---------------- host ----------------

extern "C" void kernel_launch(void* const* d_in, const int* in_sizes, int n_in,
                              void* d_out, int out_size, void* d_ws, size_t ws_size,
                              hipStream_t stream) {
  const float* enc_h    = (const float*)d_in[0];
  const float* prev_s   = (const float*)d_in[1];
  const int*   target   = (const int*)d_in[2];
  const float* embed    = (const float*)d_in[3];
  const float* att_Wenc = (const float*)d_in[4];
  const float* att_benc = (const float*)d_in[5];
  const float* att_Wprev= (const float*)d_in[6];
  const float* att_bprev= (const float*)d_in[7];
  const float* att_wlin = (const float*)d_in[8];
  const float* dc_Wi    = (const float*)d_in[10];
  const float* dc_bi    = (const float*)d_in[11];
  const float* dc_Wh    = (const float*)d_in[12];
  const float* dc_bh    = (const float*)d_in[13];
  const float* dc_Wc    = (const float*)d_in[14];
  const float* dc_bc    = (const float*)d_in[15];
  const float* dc_Wi2   = (const float*)d_in[16];
  const float* dc_bi2   = (const float*)d_in[17];
  const float* dc_Wh2   = (const float*)d_in[18];
  const float* dc_bh2   = (const float*)d_in[19];
  const float* dc_Wc2   = (const float*)d_in[20];
  const float* dc_bc2   = (const float*)d_in[21];
  const float* out_W    = (const float*)d_in[22];
  const float* out_b    = (const float*)d_in[23];

  char* w = (char*)d_ws;
  float* x    = (float*)(w + X_OFF);
  float* xgr  = (float*)(w + XGR_OFF);
  float* xg2  = (float*)(w + XG2_OFF);
  u16*  encp  = (u16*)(w + X_OFF);       // aliases x (after xgr/xg2 gemms)
  u16*  encT  = (u16*)(w + ENCT_OFF);
  u16*  wqf   = (u16*)(w + WQF_OFF);
  u16*  wgf   = (u16*)(w + WGF_OFF);
  u16*  wot   = (u16*)(w + WOT_OFF);     // aliases pool (after mega)
  u16*  dech  = (u16*)(w + DECH_OFF);
  float* sF   = (float*)(w + SF_OFF);
  u16*  sh    = (u16*)(w + SH_OFF);
  u16*  sl    = (u16*)(w + SL_OFF);
  float* qp   = (float*)(w + QP_OFF);
  u16*  ch    = (u16*)(w + CH_OFF);
  u16*  cl    = (u16*)(w + CL_OFF);
  float* scr  = (float*)(w + SC_OFF);
  float* bcr  = (float*)(w + BCR_OFF);
  float* bc2  = (float*)(w + BC2_OFF);
  int*  bar   = (int*)(w + BAR_OFF);
  float* fout = (float*)d_out + (size_t)BT_ * V_;

  hipMemsetAsync(bar, 0, 4096, stream);

  // prologue
  k_gather  <<<BT_, 128, 0, stream>>>(x, embed, target);
  k_biascomb<<<4, 256, 0, stream>>>(bcr, bc2, dc_bi, dc_bh, dc_bc, dc_bi2, dc_bh2, dc_bc2);
  k_gemm<<<16 * 8, 256, 0, stream>>>(x, E_, dc_Wi,  H2_, xgr, H_, 0, bcr, 16, 8, E_);
  k_gemm<<<16 * 8, 256, 0, stream>>>(x, E_, dc_Wi2, H_,  xg2, H_, 0, bc2, 16, 8, E_);
  k_gemm<<<16 * 8, 256, 0, stream>>>(enc_h, H2_, att_Wenc, H_, encp, H_, 1, att_benc, 16, 8, H2_);
  k_transE<<<1024, 256, 0, stream>>>(encT, enc_h);
  k_packq <<<512, 256, 0, stream>>>(wqf, att_Wprev);
  k_packg <<<6144, 256, 0, stream>>>(wgf, dc_Wh, dc_Wc, dc_Wh2, dc_Wc2);

  // the 64-step recurrence in one persistent kernel
  k_mega<<<256, 512, 0, stream>>>(sF, sh, sl, qp, ch, cl, scr, dech, fout,
                                  wqf, wgf, encp, encT, xgr, xg2,
                                  prev_s, att_bprev, att_wlin, bar);

  // vocab projection in two halves (wot aliases dead prologue workspace)
  k_wtrans<<<4000, 256, 0, stream>>>(wot, out_W, 0);
  k_gemm2 <<<2000, 256, 0, stream>>>(dech, wot, (float*)d_out, out_b, 0);
  k_wtrans<<<4000, 256, 0, stream>>>(wot, out_W, 16000);
  k_gemm2 <<<2000, 256, 0, stream>>>(dech, wot, (float*)d_out, out_b, 16000);
}

// Round 3
// 6568.143 us; speedup vs baseline: 2.5304x; 1.1636x over previous
//
#include <hip/hip_runtime.h>

// Sizes
#define B_   32
#define S_   64
#define T_   64
#define H_   1024
#define H2_  2048
#define E_   512
#define V_   32000
#define K3_  3072
#define BT_  2048

typedef unsigned short u16;
typedef __attribute__((ext_vector_type(8))) short short8_t;  // 8 x bf16
typedef __attribute__((ext_vector_type(4))) float f32x4;

__device__ __forceinline__ u16 f2bf(float f) {
  unsigned x = __float_as_uint(f);
  unsigned r = (x + 0x7fffu + ((x >> 16) & 1u)) >> 16;  // RNE
  return (u16)r;
}
__device__ __forceinline__ float bf2f(u16 h) {
  return __uint_as_float(((unsigned)h) << 16);
}
__device__ __forceinline__ float frcp(float x) { return __builtin_amdgcn_rcpf(x); }
__device__ __forceinline__ float ftanh(float x) {
  float e = __expf(2.f * x);
  return 1.f - 2.f * frcp(e + 1.f);
}
__device__ __forceinline__ float fsigm(float x) {
  return frcp(1.f + __expf(-x));
}

// ---------------- workspace layout (bytes) ----------------
#define MB_ (1ull << 20)
#define KB_ (1ull << 10)
#define X_OFF    (0)              // 4MB; encp aliases after xgr/xg2 gemms
#define XGR_OFF  (4*MB_)          // 8MB
#define XG2_OFF  (12*MB_)         // 8MB
#define ENCT_OFF (20*MB_)         // 8MB
#define WQF_OFF  (28*MB_)         // 2MB
#define WGF_OFF  (30*MB_)         // 24MB
#define WOT_OFF  (0)              // ~33MB (after mega only)
#define DECH_OFF (54*MB_)         // 4MB
#define SF_OFF   (58*MB_)                 // 2 x 128KB
#define XH_OFF   (58*MB_ + 256*KB_)       // 2 x 192KB  ([s|ctx] hi, [32][3072])
#define XL_OFF   (58*MB_ + 640*KB_)       // 2 x 192KB  ([s|ctx] lo)
#define QP_OFF   (58*MB_ + 1024*KB_)      // 512KB (4 x 32 x 1024 f32)
#define BAS_OFF  (58*MB_ + 1536*KB_)      // 4KB (benc+bprev)
#define BCR_OFF  (58*MB_ + 1540*KB_)      // 4KB
#define BC2_OFF  (58*MB_ + 1544*KB_)      // 4KB
#define WLB_OFF  (58*MB_ + 1548*KB_)      // 2KB (wlin bf16)
#define BAR_OFF  (58*MB_ + 1552*KB_)      // 4KB

// ---------------- prologue kernels ----------------

__global__ void k_gather(float* __restrict__ x, const float* __restrict__ embed,
                         const int* __restrict__ tgt) {
  int bid = blockIdx.x;              // t*B + b
  int t = bid >> 5, b = bid & 31;
  int row = tgt[b * T_ + t];
  const float4* src = (const float4*)(embed + (size_t)row * E_);
  float4* dst = (float4*)(x + (size_t)bid * E_);
  dst[threadIdx.x] = src[threadIdx.x];
}

__global__ void k_biascomb(float* bcr, float* bc2o, float* bas, u16* wlb,
                           const float* bi, const float* bh, const float* bc,
                           const float* bi2, const float* bh2, const float* bc2i,
                           const float* benc, const float* bprev, const float* wlin) {
  int j = blockIdx.x * 256 + threadIdx.x;
  if (j < H_) {
    bcr[j]  = bi[j]  + bh[j]  + bc[j];
    bc2o[j] = bi2[j] + bh2[j] + bc2i[j];
    bas[j]  = benc[j] + bprev[j];
    wlb[j]  = f2bf(wlin[j]);
  }
}

// generic 128x128 bf16-MFMA GEMM (fp32 in, fp32/bf16 out) — prologue only
__global__ __launch_bounds__(256) void k_gemm(
    const float* __restrict__ A, int lda,
    const float* __restrict__ Bm, int ldb,
    void* __restrict__ Cv, int ldc, int outBf16,
    const float* __restrict__ bias,
    int mtiles, int ntiles, int K) {
  __shared__ u16 As[128][72];
  __shared__ u16 Bs[128][72];
  int nwg = mtiles * ntiles;
  int bid = blockIdx.x;
  int cpx = nwg >> 3;
  int lb = (bid & 7) * cpx + (bid >> 3);
  int ntb = lb / mtiles, mtb = lb - ntb * mtiles;
  size_t m0 = (size_t)mtb * 128, n0 = (size_t)ntb * 128;
  int t = threadIdx.x, lane = t & 63, wid = t >> 6;
  int wr = (wid >> 1) * 64, wc = (wid & 1) * 64;
  f32x4 acc[4][4] = {};
  for (int k0 = 0; k0 < K; k0 += 64) {
    #pragma unroll
    for (int i = 0; i < 8; ++i) {
      int f4 = i * 256 + t;
      int row = f4 >> 4, c4 = (f4 & 15) << 2;
      float4 v = *(const float4*)(A + (m0 + row) * (size_t)lda + k0 + c4);
      ushort4 u; u.x = f2bf(v.x); u.y = f2bf(v.y); u.z = f2bf(v.z); u.w = f2bf(v.w);
      *(ushort4*)&As[row][c4] = u;
    }
    #pragma unroll
    for (int i = 0; i < 8; ++i) {
      int f4 = i * 256 + t;
      int kr = f4 >> 5, c4 = (f4 & 31) << 2;
      float4 v = *(const float4*)(Bm + (size_t)(k0 + kr) * ldb + n0 + c4);
      Bs[c4 + 0][kr] = f2bf(v.x);
      Bs[c4 + 1][kr] = f2bf(v.y);
      Bs[c4 + 2][kr] = f2bf(v.z);
      Bs[c4 + 3][kr] = f2bf(v.w);
    }
    __syncthreads();
    #pragma unroll
    for (int kk = 0; kk < 64; kk += 32) {
      int ko = kk + (lane >> 4) * 8;
      short8_t am[4], bn[4];
      #pragma unroll
      for (int m = 0; m < 4; ++m) am[m] = *(const short8_t*)&As[wr + m * 16 + (lane & 15)][ko];
      #pragma unroll
      for (int n = 0; n < 4; ++n) bn[n] = *(const short8_t*)&Bs[wc + n * 16 + (lane & 15)][ko];
      #pragma unroll
      for (int m = 0; m < 4; ++m)
        #pragma unroll
        for (int n = 0; n < 4; ++n)
          acc[m][n] = __builtin_amdgcn_mfma_f32_16x16x32_bf16(am[m], bn[n], acc[m][n], 0, 0, 0);
    }
    __syncthreads();
  }
  #pragma unroll
  for (int n = 0; n < 4; ++n) {
    int col = wc + n * 16 + (lane & 15);
    float bv = bias ? bias[n0 + col] : 0.f;
    #pragma unroll
    for (int m = 0; m < 4; ++m) {
      size_t row = m0 + wr + m * 16 + ((lane >> 4) << 2);
      #pragma unroll
      for (int r = 0; r < 4; ++r) {
        float val = acc[m][n][r] + bv;
        if (outBf16) ((u16*)Cv)[(row + r) * (size_t)ldc + n0 + col] = f2bf(val);
        else ((float*)Cv)[(row + r) * (size_t)ldc + n0 + col] = val;
      }
    }
  }
}

// enc_h -> encT[e][b*64+si] bf16
__global__ __launch_bounds__(256) void k_transE(u16* __restrict__ encT,
                                                const float* __restrict__ enc_h) {
  __shared__ u16 ld[64][68];
  int b = blockIdx.x >> 5, et = blockIdx.x & 31;
  int e0 = et * 64;
  int t = threadIdx.x;
  #pragma unroll
  for (int i = 0; i < 4; ++i) {
    int f4 = i * 256 + t;
    int si = f4 >> 4, e4 = (f4 & 15) << 2;
    float4 v = *(const float4*)(enc_h + ((size_t)(b * 64 + si)) * H2_ + e0 + e4);
    ld[si][e4 + 0] = f2bf(v.x); ld[si][e4 + 1] = f2bf(v.y);
    ld[si][e4 + 2] = f2bf(v.z); ld[si][e4 + 3] = f2bf(v.w);
  }
  __syncthreads();
  #pragma unroll
  for (int i = 0; i < 2; ++i) {
    int idx = i * 256 + t;
    int e = idx >> 3, s8 = (idx & 7) << 3;
    short8_t o;
    #pragma unroll
    for (int k = 0; k < 8; ++k) o[k] = (short)ld[s8 + k][e];
    *(short8_t*)(encT + ((size_t)(e0 + e)) * 2048 + b * 64 + s8) = o;
  }
}

// att_Wprev -> wqf frag-major bf16: lin = ((g*32+KB)*4+sub)*16+c, elem j:
// value = W[KB*32+sub*8+j][g*16+c]   (LDS-tiled, coalesced source reads)
__global__ __launch_bounds__(256) void k_packq(u16* __restrict__ wqf,
                                               const float* __restrict__ W) {
  __shared__ float ld[64][33];
  int jt = blockIdx.x & 31, kt = blockIdx.x >> 5;   // 32 x 16
  int c0 = jt * 32, k0 = kt * 64;
  int t = threadIdx.x;
  #pragma unroll
  for (int i = 0; i < 8; ++i) {
    int idx = i * 256 + t; int kr = idx >> 5, jc = idx & 31;
    ld[kr][jc] = W[(size_t)(k0 + kr) * H_ + c0 + jc];
  }
  __syncthreads();
  int u = t;
  int gl = u >> 7, kbl = (u >> 6) & 1, sub = (u >> 4) & 3, c = u & 15;
  int colLoc = gl * 16 + c;
  int gG = jt * 2 + gl, KB = kt * 2 + kbl;
  size_t lin = ((size_t)(gG * 32 + KB) * 4 + sub) * 16 + c;
  short8_t o;
  #pragma unroll
  for (int j = 0; j < 8; ++j) o[j] = (short)f2bf(ld[kbl * 32 + sub * 8 + j][colLoc]);
  *(short8_t*)(wqf + lin * 8) = o;
}

// gate weights -> wgf frag-major (hi in c<8, lo in c>=8), LDS-tiled
__global__ __launch_bounds__(256) void k_packg(
    u16* __restrict__ wgf, const float* __restrict__ Wh, const float* __restrict__ Wc,
    const float* __restrict__ Wh2, const float* __restrict__ Wc2) {
  __shared__ float ld[64][33];
  int sel = blockIdx.x & 1;
  int jt  = (blockIdx.x >> 1) & 31;
  int kt  = blockIdx.x >> 6;          // 0..47
  int k0 = kt * 64, j0 = jt * 32;
  int t = threadIdx.x;
  const float* srcW = (k0 < H_) ? (sel ? Wh2 : Wh) : (sel ? Wc2 : Wc);
  int ldw = sel ? H_ : H2_;
  int koff = (k0 < H_) ? k0 : (k0 - H_);
  #pragma unroll
  for (int i = 0; i < 8; ++i) {
    int idx = i * 256 + t; int kr = idx >> 5, jc = idx & 31;
    ld[kr][jc] = srcW[(size_t)(koff + kr) * ldw + j0 + jc];
  }
  __syncthreads();
  #pragma unroll
  for (int it = 0; it < 2; ++it) {
    int u = it * 256 + t;
    int m = u & 3, sub = (u >> 2) & 3, kbl = (u >> 4) & 1, islo = (u >> 5) & 1, gg = u >> 6;
    int jjLoc = gg * 4 + m;
    int p = 2 * (j0 + jjLoc) + sel;
    int g = p >> 3, cc = p & 7;
    int c = cc + 8 * islo;
    int KB = kt * 2 + kbl;
    size_t lin = ((size_t)(g * 96 + KB) * 4 + sub) * 16 + c;
    short8_t o;
    #pragma unroll
    for (int j = 0; j < 8; ++j) {
      float v = ld[kbl * 32 + sub * 8 + j][jjLoc];
      u16 h = f2bf(v);
      o[j] = (short)(islo ? f2bf(v - bf2f(h)) : h);
    }
    *(short8_t*)(wgf + lin * 8) = o;
  }
}

// out_W half -> wot bf16 [nLocal 16000][k 1024]
__global__ __launch_bounds__(256) void k_wtrans(u16* __restrict__ wot,
                                                const float* __restrict__ W, int nbase) {
  __shared__ u16 ld[64][68];
  int nt = blockIdx.x % 250, kt = blockIdx.x / 250;
  int n0 = nbase + nt * 64, k0 = kt * 64;
  int t = threadIdx.x;
  #pragma unroll
  for (int i = 0; i < 4; ++i) {
    int f4 = i * 256 + t;
    int kr = f4 >> 4, n4 = (f4 & 15) << 2;
    float4 v = *(const float4*)(W + (size_t)(k0 + kr) * V_ + n0 + n4);
    ld[kr][n4 + 0] = f2bf(v.x); ld[kr][n4 + 1] = f2bf(v.y);
    ld[kr][n4 + 2] = f2bf(v.z); ld[kr][n4 + 3] = f2bf(v.w);
  }
  __syncthreads();
  #pragma unroll
  for (int i = 0; i < 2; ++i) {
    int idx = i * 256 + t;
    int n = idx >> 3, k8 = (idx & 7) << 3;
    short8_t o;
    #pragma unroll
    for (int k = 0; k < 8; ++k) o[k] = (short)ld[k8 + k][n];
    *(short8_t*)(wot + ((size_t)(nt * 64 + n)) * H_ + k0 + k8) = o;
  }
}

// final GEMM: dech bf16 [2048][1024] @ wot^T -> C fp32 (per 16000-col half)
__global__ __launch_bounds__(256) void k_gemm2(
    const u16* __restrict__ A, const u16* __restrict__ Bt,
    float* __restrict__ C, const float* __restrict__ bias, int n0g) {
  __shared__ u16 As[128][72];
  __shared__ u16 Bs[128][72];
  int bid = blockIdx.x;
  int lb = (bid & 7) * 250 + (bid >> 3);
  int mtb = lb & 15, ntb = lb >> 4;
  size_t m0 = (size_t)mtb * 128;
  size_t nl0 = (size_t)ntb * 128;
  int t = threadIdx.x, lane = t & 63, wid = t >> 6;
  int wr = (wid >> 1) * 64, wc = (wid & 1) * 64;
  f32x4 acc[4][4] = {};
  for (int k0 = 0; k0 < H_; k0 += 64) {
    #pragma unroll
    for (int i = 0; i < 4; ++i) {
      int idx = i * 256 + t;
      int row = idx >> 3, c8 = (idx & 7) << 3;
      *(short8_t*)&As[row][c8] = *(const short8_t*)(A + (m0 + row) * H_ + k0 + c8);
      *(short8_t*)&Bs[row][c8] = *(const short8_t*)(Bt + (nl0 + row) * H_ + k0 + c8);
    }
    __syncthreads();
    #pragma unroll
    for (int kk = 0; kk < 64; kk += 32) {
      int ko = kk + (lane >> 4) * 8;
      short8_t am[4], bn[4];
      #pragma unroll
      for (int m = 0; m < 4; ++m) am[m] = *(const short8_t*)&As[wr + m * 16 + (lane & 15)][ko];
      #pragma unroll
      for (int n = 0; n < 4; ++n) bn[n] = *(const short8_t*)&Bs[wc + n * 16 + (lane & 15)][ko];
      #pragma unroll
      for (int m = 0; m < 4; ++m)
        #pragma unroll
        for (int n = 0; n < 4; ++n)
          acc[m][n] = __builtin_amdgcn_mfma_f32_16x16x32_bf16(am[m], bn[n], acc[m][n], 0, 0, 0);
    }
    __syncthreads();
  }
  #pragma unroll
  for (int n = 0; n < 4; ++n) {
    int col = n0g + (int)nl0 + wc + n * 16 + (lane & 15);
    float bv = bias[col];
    #pragma unroll
    for (int m = 0; m < 4; ++m) {
      size_t row = m0 + wr + m * 16 + ((lane >> 4) << 2);
      #pragma unroll
      for (int r = 0; r < 4; ++r)
        C[(row + r) * (size_t)V_ + col] = acc[m][n][r] + bv;
    }
  }
}

// ---------------- persistent decoder kernel ----------------

__device__ __forceinline__ void gridbar(int* bar, int target) {
  __syncthreads();
  if (threadIdx.x == 0) {
    int* leaf  = bar;                 // 32 x 16 ints
    int* root  = bar + 512;
    int* epoch = bar + 528;
    int li = (blockIdx.x >> 3) * 16;
    if (__hip_atomic_fetch_add(&leaf[li], 1, __ATOMIC_ACQ_REL, __HIP_MEMORY_SCOPE_AGENT) == 7) {
      __hip_atomic_store(&leaf[li], 0, __ATOMIC_RELAXED, __HIP_MEMORY_SCOPE_AGENT);
      if (__hip_atomic_fetch_add(root, 1, __ATOMIC_ACQ_REL, __HIP_MEMORY_SCOPE_AGENT) == 31) {
        __hip_atomic_store(root, 0, __ATOMIC_RELAXED, __HIP_MEMORY_SCOPE_AGENT);
        __hip_atomic_store(epoch, target, __ATOMIC_RELEASE, __HIP_MEMORY_SCOPE_AGENT);
      }
    }
    while (__hip_atomic_load(epoch, __ATOMIC_RELAXED, __HIP_MEMORY_SCOPE_AGENT) != target)
      __builtin_amdgcn_s_sleep(1);
    __threadfence();
  }
  __syncthreads();
}

#define MFMA16(a, b, c) __builtin_amdgcn_mfma_f32_16x16x32_bf16((a), (b), (c), 0, 0, 0)

__global__ __launch_bounds__(512, 2) void k_mega(
    float* __restrict__ sF, u16* __restrict__ Xh, u16* __restrict__ Xl,
    float* __restrict__ qp, u16* __restrict__ dech, float* __restrict__ fout,
    const u16* __restrict__ wqf, const u16* __restrict__ wgf,
    const u16* __restrict__ encp, const u16* __restrict__ encT,
    const float* __restrict__ xgr, const float* __restrict__ xg2,
    const float* __restrict__ prev_s, const u16* __restrict__ wlb,
    int* bar) {
  const int t = threadIdx.x, blk = blockIdx.x;
  const int lane = t & 63, wid = t >> 6;
  const int l15 = lane & 15, l4 = lane >> 4;
  const int klo = l4 * 8;
  __shared__ f32x4 scr[1024];      // 16KB reduce scratch
  __shared__ float sc[64];
  int ep = 0;

  // ---- resident (register) step-invariant operands, loaded ONCE ----
  // P1: block (g1 = blk&63, kq1 = blk>>6); wave owns kb = kq1*8+wid
  const int g1 = blk & 63, kq1 = blk >> 6;
  const int kbq = kq1 * 8 + wid;
  const short8_t wq0 = *(const short8_t*)(wqf + ((size_t)(g1 * 32 + kbq) * 64 + lane) * 8);

  // P4: wave owns kb in [wid*12, wid*12+12)
  short8_t wg[12];
  #pragma unroll
  for (int i = 0; i < 12; ++i)
    wg[i] = *(const short8_t*)(wgf + ((size_t)blk * 6144 + (size_t)(wid * 12 + i) * 64 + lane) * 8);

  // P2': b = blk>>3, eg = blk&7 ; wave covers si = wid*8..+8, lane covers j = lane*16..+16
  const int bb = blk >> 3, eg = blk & 7;
  short8_t epv[8][2];
  #pragma unroll
  for (int r = 0; r < 8; ++r) {
    const u16* p = encp + ((size_t)(bb * 64 + wid * 8 + r)) * H_ + lane * 16;
    epv[r][0] = *(const short8_t*)(p);
    epv[r][1] = *(const short8_t*)(p + 8);
  }
  short8_t wlv[2];
  wlv[0] = *(const short8_t*)(wlb + lane * 16);
  wlv[1] = *(const short8_t*)(wlb + lane * 16 + 8);

  const int eloc = t >> 1, half = t & 1;
  const int ecol = eg * 256 + eloc;
  short8_t et[4];
  #pragma unroll
  for (int i = 0; i < 4; ++i)
    et[i] = *(const short8_t*)(encT + (size_t)ecol * 2048 + bb * 64 + half * 32 + i * 8);

  // P0: init state
  {
    int idx = blk * 512 + t;
    if (idx < B_ * H_) {
      int row = idx >> 10, j = idx & 1023;
      float v = prev_s[idx];
      sF[idx] = v;
      u16 h = f2bf(v);
      Xh[row * K3_ + j] = h;
      Xl[row * K3_ + j] = f2bf(v - bf2f(h));
    }
  }
  gridbar(bar, ++ep);

  for (int ts = 0; ts < T_; ++ts) {
    const int pb = ts & 1;
    const u16* XhC = Xh + pb * (B_ * K3_);
    const u16* XlC = Xl + pb * (B_ * K3_);
    u16* XhCw = Xh + pb * (B_ * K3_);
    u16* XlCw = Xl + pb * (B_ * K3_);
    u16* XhN = Xh + (pb ^ 1) * (B_ * K3_);
    u16* XlN = Xl + (pb ^ 1) * (B_ * K3_);
    const float* sFc = sF + pb * (B_ * H_);
    float* sFn = sF + (pb ^ 1) * (B_ * H_);

    // prefetch xg operands for P4 epilogue (finalizer threads only)
    float xv[4] = {0.f, 0.f, 0.f, 0.f};
    const int pc4 = blk * 8 + l15, jcol = pc4 >> 1, isc = pc4 & 1;
    const int rb = wid * 16 + l4 * 4;
    if (wid < 2 && l15 < 8) {
      const float* xg = isc ? xg2 : xgr;
      #pragma unroll
      for (int r = 0; r < 4; ++r)
        xv[r] = xg[((size_t)ts * B_ + rb + r) * H_ + jcol];
    }

    // ---- P1: q partials (s @ Wprev) ----
    {
      const u16* arow = XhC + kbq * 32 + klo;
      short8_t avA = *(const short8_t*)(arow + l15 * K3_);
      short8_t avB = *(const short8_t*)(arow + (l15 + 16) * K3_);
      f32x4 aA = {}, aB = {};
      aA = MFMA16(avA, wq0, aA);
      aB = MFMA16(avB, wq0, aB);
      scr[(wid * 2 + 0) * 64 + lane] = aA;
      scr[(wid * 2 + 1) * 64 + lane] = aB;
      __syncthreads();
      if (wid < 2) {
        f32x4 s = scr[wid * 64 + lane];
        #pragma unroll
        for (int i = 1; i < 8; ++i) s += scr[(i * 2 + wid) * 64 + lane];
        int col = g1 * 16 + l15;
        #pragma unroll
        for (int r = 0; r < 4; ++r)
          qp[((size_t)(kq1 * 32) + rb + r) * H_ + col] = s[r];
      }
    }
    gridbar(bar, ++ep);

    // ---- P2': scores + softmax + ctx (per-b, 8-way redundant scores) ----
    {
      float qv[16];
      #pragma unroll
      for (int i = 0; i < 4; ++i) {
        float4 s0 = *(const float4*)(qp + (size_t)bb * H_ + lane * 16 + i * 4);
        #pragma unroll
        for (int kq = 1; kq < 4; ++kq) {
          float4 pq = *(const float4*)(qp + ((size_t)(kq * 32) + bb) * H_ + lane * 16 + i * 4);
          s0.x += pq.x; s0.y += pq.y; s0.z += pq.z; s0.w += pq.w;
        }
        qv[i * 4 + 0] = s0.x; qv[i * 4 + 1] = s0.y;
        qv[i * 4 + 2] = s0.z; qv[i * 4 + 3] = s0.w;
      }
      #pragma unroll
      for (int r = 0; r < 8; ++r) {
        float p = 0.f;
        #pragma unroll
        for (int jj = 0; jj < 16; ++jj)
          p += ftanh(bf2f((u16)epv[r][jj >> 3][jj & 7]) + qv[jj]) * bf2f((u16)wlv[jj >> 3][jj & 7]);
        #pragma unroll
        for (int off = 32; off; off >>= 1) p += __shfl_xor(p, off, 64);
        if (lane == 0) sc[wid * 8 + r] = p;
      }
      __syncthreads();
      {
        float v = sc[lane];
        float m = v;
        #pragma unroll
        for (int off = 32; off; off >>= 1) m = fmaxf(m, __shfl_xor(m, off, 64));
        float e = __expf(v - m);
        float s = e;
        #pragma unroll
        for (int off = 32; off; off >>= 1) s += __shfl_xor(s, off, 64);
        if (wid == 0) sc[lane] = e * frcp(s);
      }
      __syncthreads();
      {
        float a = 0.f;
        #pragma unroll
        for (int i = 0; i < 4; ++i)
          #pragma unroll
          for (int j = 0; j < 8; ++j)
            a += sc[half * 32 + i * 8 + j] * bf2f((u16)et[i][j]);
        a += __shfl_xor(a, 1, 64);
        if (half == 0) {
          u16 hh = f2bf(a);
          XhCw[bb * K3_ + H_ + ecol] = hh;
          XlCw[bb * K3_ + H_ + ecol] = f2bf(a - bf2f(hh));
        }
      }
    }
    gridbar(bar, ++ep);

    // ---- P4: gates ([s|ctx] @ Wcat split-bf16) + state update ----
    {
      f32x4 aA = {}, aB = {};
      const u16* ah = XhC + klo;
      const u16* al = XlC + klo;
      #pragma unroll
      for (int i = 0; i < 12; ++i) {
        int kof = (wid * 12 + i) * 32;
        short8_t hA = *(const short8_t*)(ah + l15 * K3_ + kof);
        short8_t lA = *(const short8_t*)(al + l15 * K3_ + kof);
        short8_t hB = *(const short8_t*)(ah + (l15 + 16) * K3_ + kof);
        short8_t lB = *(const short8_t*)(al + (l15 + 16) * K3_ + kof);
        aA = MFMA16(hA, wg[i], aA);
        aA = MFMA16(lA, wg[i], aA);
        aB = MFMA16(hB, wg[i], aB);
        aB = MFMA16(lB, wg[i], aB);
      }
      scr[(wid * 2 + 0) * 64 + lane] = aA;
      scr[(wid * 2 + 1) * 64 + lane] = aB;
      __syncthreads();
      if (wid < 2) {
        f32x4 s = scr[wid * 64 + lane];
        #pragma unroll
        for (int i = 1; i < 8; ++i) s += scr[(i * 2 + wid) * 64 + lane];
        float tot[4];
        #pragma unroll
        for (int r = 0; r < 4; ++r) tot[r] = s[r] + __shfl_xor(s[r], 8, 64);
        if (l15 < 8) {
          #pragma unroll
          for (int r = 0; r < 4; ++r) {
            int brow = rb + r;
            float pre = tot[r] + xv[r];
            float mate = __shfl_xor(pre, 1, 64);
            float rpre = isc ? mate : pre;
            float cpre = isc ? pre : mate;
            float rg = fsigm(rpre);
            float cg = ftanh(cpre);
            float sp = sFc[brow * H_ + jcol];
            float sn = sp + rg * (cg - sp);
            if (!isc) {
              sFn[brow * H_ + jcol] = sn;
              u16 hh = f2bf(sn);
              XhN[brow * K3_ + jcol] = hh;
              XlN[brow * K3_ + jcol] = f2bf(sn - bf2f(hh));
              dech[((size_t)brow * T_ + ts) * H_ + jcol] = hh;
              if (ts == T_ - 1) fout[brow * H_ + jcol] = sn;
            }
          }
        }
      }
    }
    gridbar(bar, ++ep);
  }
}

// ---------------- host ----------------

extern "C" void kernel_launch(void* const* d_in, const int* in_sizes, int n_in,
                              void* d_out, int out_size, void* d_ws, size_t ws_size,
                              hipStream_t stream) {
  const float* enc_h    = (const float*)d_in[0];
  const float* prev_s   = (const float*)d_in[1];
  const int*   target   = (const int*)d_in[2];
  const float* embed    = (const float*)d_in[3];
  const float* att_Wenc = (const float*)d_in[4];
  const float* att_benc = (const float*)d_in[5];
  const float* att_Wprev= (const float*)d_in[6];
  const float* att_bprev= (const float*)d_in[7];
  const float* att_wlin = (const float*)d_in[8];
  const float* dc_Wi    = (const float*)d_in[10];
  const float* dc_bi    = (const float*)d_in[11];
  const float* dc_Wh    = (const float*)d_in[12];
  const float* dc_bh    = (const float*)d_in[13];
  const float* dc_Wc    = (const float*)d_in[14];
  const float* dc_bc    = (const float*)d_in[15];
  const float* dc_Wi2   = (const float*)d_in[16];
  const float* dc_bi2   = (const float*)d_in[17];
  const float* dc_Wh2   = (const float*)d_in[18];
  const float* dc_bh2   = (const float*)d_in[19];
  const float* dc_Wc2   = (const float*)d_in[20];
  const float* dc_bc2   = (const float*)d_in[21];
  const float* out_W    = (const float*)d_in[22];
  const float* out_b    = (const float*)d_in[23];

  char* w = (char*)d_ws;
  float* x    = (float*)(w + X_OFF);
  float* xgr  = (float*)(w + XGR_OFF);
  float* xg2  = (float*)(w + XG2_OFF);
  u16*  encp  = (u16*)(w + X_OFF);       // aliases x (after xgr/xg2 gemms)
  u16*  encT  = (u16*)(w + ENCT_OFF);
  u16*  wqf   = (u16*)(w + WQF_OFF);
  u16*  wgf   = (u16*)(w + WGF_OFF);
  u16*  wot   = (u16*)(w + WOT_OFF);     // aliases pool (after mega)
  u16*  dech  = (u16*)(w + DECH_OFF);
  float* sF   = (float*)(w + SF_OFF);
  u16*  Xh    = (u16*)(w + XH_OFF);
  u16*  Xl    = (u16*)(w + XL_OFF);
  float* qp   = (float*)(w + QP_OFF);
  float* bas  = (float*)(w + BAS_OFF);
  float* bcr  = (float*)(w + BCR_OFF);
  float* bc2  = (float*)(w + BC2_OFF);
  u16*  wlb   = (u16*)(w + WLB_OFF);
  int*  bar   = (int*)(w + BAR_OFF);
  float* fout = (float*)d_out + (size_t)BT_ * V_;

  hipMemsetAsync(bar, 0, 4096, stream);

  // prologue
  k_gather  <<<BT_, 128, 0, stream>>>(x, embed, target);
  k_biascomb<<<4, 256, 0, stream>>>(bcr, bc2, bas, wlb,
                                    dc_bi, dc_bh, dc_bc, dc_bi2, dc_bh2, dc_bc2,
                                    att_benc, att_bprev, att_wlin);
  k_gemm<<<16 * 8, 256, 0, stream>>>(x, E_, dc_Wi,  H2_, xgr, H_, 0, bcr, 16, 8, E_);
  k_gemm<<<16 * 8, 256, 0, stream>>>(x, E_, dc_Wi2, H_,  xg2, H_, 0, bc2, 16, 8, E_);
  k_gemm<<<16 * 8, 256, 0, stream>>>(enc_h, H2_, att_Wenc, H_, encp, H_, 1, bas, 16, 8, H2_);
  k_transE<<<1024, 256, 0, stream>>>(encT, enc_h);
  k_packq <<<512, 256, 0, stream>>>(wqf, att_Wprev);
  k_packg <<<3072, 256, 0, stream>>>(wgf, dc_Wh, dc_Wc, dc_Wh2, dc_Wc2);

  // the 64-step recurrence in one persistent kernel (weights in registers)
  k_mega<<<256, 512, 0, stream>>>(sF, Xh, Xl, qp, dech, fout,
                                  wqf, wgf, encp, encT, xgr, xg2,
                                  prev_s, wlb, bar);

  // vocab projection in two halves (wot aliases dead prologue workspace)
  k_wtrans<<<4000, 256, 0, stream>>>(wot, out_W, 0);
  k_gemm2 <<<2000, 256, 0, stream>>>(dech, wot, (float*)d_out, out_b, 0);
  k_wtrans<<<4000, 256, 0, stream>>>(wot, out_W, 16000);
  k_gemm2 <<<2000, 256, 0, stream>>>(dech, wot, (float*)d_out, out_b, 16000);
}

// Round 4
// 5511.936 us; speedup vs baseline: 3.0152x; 1.1916x over previous
//
#include <hip/hip_runtime.h>

// Sizes
#define B_   32
#define S_   64
#define T_   64
#define H_   1024
#define H2_  2048
#define E_   512
#define V_   32000
#define K3_  3072
#define BT_  2048

typedef unsigned short u16;
typedef __attribute__((ext_vector_type(8))) short short8_t;  // 8 x bf16
typedef __attribute__((ext_vector_type(4))) float f32x4;

__device__ __forceinline__ u16 f2bf(float f) {
  unsigned x = __float_as_uint(f);
  unsigned r = (x + 0x7fffu + ((x >> 16) & 1u)) >> 16;  // RNE
  return (u16)r;
}
__device__ __forceinline__ float bf2f(u16 h) {
  return __uint_as_float(((unsigned)h) << 16);
}
__device__ __forceinline__ float frcp(float x) { return __builtin_amdgcn_rcpf(x); }
__device__ __forceinline__ float ftanh(float x) {
  float e = __expf(2.f * x);
  return 1.f - 2.f * frcp(e + 1.f);
}
__device__ __forceinline__ float fsigm(float x) {
  return frcp(1.f + __expf(-x));
}

// pin a loaded value in VGPRs: opaque asm result cannot be rematerialized
#define KEEPV(x) asm volatile("" : "+v"(x))

// ---------------- workspace layout (bytes) ----------------
#define MB_ (1ull << 20)
#define KB_ (1ull << 10)
#define X_OFF    (0)              // 4MB; encp aliases after xgr/xg2 gemms
#define XGR_OFF  (4*MB_)          // 8MB
#define XG2_OFF  (12*MB_)         // 8MB
#define ENCT_OFF (20*MB_)         // 8MB
#define WQF_OFF  (28*MB_)         // 2MB
#define WGF_OFF  (30*MB_)         // 24MB
#define WOT_OFF  (0)              // ~33MB (after mega only)
#define DECH_OFF (54*MB_)         // 4MB
#define XH_OFF   (58*MB_ + 256*KB_)       // 2 x 192KB  ([s|ctx] hi, [32][3072])
#define XL_OFF   (58*MB_ + 640*KB_)       // 2 x 192KB  ([s|ctx] lo)
#define QF_OFF   (58*MB_ + 1024*KB_)      // 128KB (32 x 1024 f32)
#define BAS_OFF  (58*MB_ + 1536*KB_)      // 4KB (benc+bprev)
#define BCR_OFF  (58*MB_ + 1540*KB_)      // 4KB
#define BC2_OFF  (58*MB_ + 1544*KB_)      // 4KB
#define WLB_OFF  (58*MB_ + 1548*KB_)      // 2KB (wlin bf16)
#define BAR_OFF  (58*MB_ + 1552*KB_)      // 4KB

// ---------------- prologue kernels ----------------

__global__ void k_gather(float* __restrict__ x, const float* __restrict__ embed,
                         const int* __restrict__ tgt) {
  int bid = blockIdx.x;              // t*B + b
  int t = bid >> 5, b = bid & 31;
  int row = tgt[b * T_ + t];
  const float4* src = (const float4*)(embed + (size_t)row * E_);
  float4* dst = (float4*)(x + (size_t)bid * E_);
  dst[threadIdx.x] = src[threadIdx.x];
}

__global__ void k_biascomb(float* bcr, float* bc2o, float* bas, u16* wlb,
                           const float* bi, const float* bh, const float* bc,
                           const float* bi2, const float* bh2, const float* bc2i,
                           const float* benc, const float* bprev, const float* wlin) {
  int j = blockIdx.x * 256 + threadIdx.x;
  if (j < H_) {
    bcr[j]  = bi[j]  + bh[j]  + bc[j];
    bc2o[j] = bi2[j] + bh2[j] + bc2i[j];
    bas[j]  = benc[j] + bprev[j];
    wlb[j]  = f2bf(wlin[j]);
  }
}

// generic 128x128 bf16-MFMA GEMM (fp32 in, fp32/bf16 out) — prologue only
__global__ __launch_bounds__(256) void k_gemm(
    const float* __restrict__ A, int lda,
    const float* __restrict__ Bm, int ldb,
    void* __restrict__ Cv, int ldc, int outBf16,
    const float* __restrict__ bias,
    int mtiles, int ntiles, int K) {
  __shared__ u16 As[128][72];
  __shared__ u16 Bs[128][72];
  int nwg = mtiles * ntiles;
  int bid = blockIdx.x;
  int cpx = nwg >> 3;
  int lb = (bid & 7) * cpx + (bid >> 3);
  int ntb = lb / mtiles, mtb = lb - ntb * mtiles;
  size_t m0 = (size_t)mtb * 128, n0 = (size_t)ntb * 128;
  int t = threadIdx.x, lane = t & 63, wid = t >> 6;
  int wr = (wid >> 1) * 64, wc = (wid & 1) * 64;
  f32x4 acc[4][4] = {};
  for (int k0 = 0; k0 < K; k0 += 64) {
    #pragma unroll
    for (int i = 0; i < 8; ++i) {
      int f4 = i * 256 + t;
      int row = f4 >> 4, c4 = (f4 & 15) << 2;
      float4 v = *(const float4*)(A + (m0 + row) * (size_t)lda + k0 + c4);
      ushort4 u; u.x = f2bf(v.x); u.y = f2bf(v.y); u.z = f2bf(v.z); u.w = f2bf(v.w);
      *(ushort4*)&As[row][c4] = u;
    }
    #pragma unroll
    for (int i = 0; i < 8; ++i) {
      int f4 = i * 256 + t;
      int kr = f4 >> 5, c4 = (f4 & 31) << 2;
      float4 v = *(const float4*)(Bm + (size_t)(k0 + kr) * ldb + n0 + c4);
      Bs[c4 + 0][kr] = f2bf(v.x);
      Bs[c4 + 1][kr] = f2bf(v.y);
      Bs[c4 + 2][kr] = f2bf(v.z);
      Bs[c4 + 3][kr] = f2bf(v.w);
    }
    __syncthreads();
    #pragma unroll
    for (int kk = 0; kk < 64; kk += 32) {
      int ko = kk + (lane >> 4) * 8;
      short8_t am[4], bn[4];
      #pragma unroll
      for (int m = 0; m < 4; ++m) am[m] = *(const short8_t*)&As[wr + m * 16 + (lane & 15)][ko];
      #pragma unroll
      for (int n = 0; n < 4; ++n) bn[n] = *(const short8_t*)&Bs[wc + n * 16 + (lane & 15)][ko];
      #pragma unroll
      for (int m = 0; m < 4; ++m)
        #pragma unroll
        for (int n = 0; n < 4; ++n)
          acc[m][n] = __builtin_amdgcn_mfma_f32_16x16x32_bf16(am[m], bn[n], acc[m][n], 0, 0, 0);
    }
    __syncthreads();
  }
  #pragma unroll
  for (int n = 0; n < 4; ++n) {
    int col = wc + n * 16 + (lane & 15);
    float bv = bias ? bias[n0 + col] : 0.f;
    #pragma unroll
    for (int m = 0; m < 4; ++m) {
      size_t row = m0 + wr + m * 16 + ((lane >> 4) << 2);
      #pragma unroll
      for (int r = 0; r < 4; ++r) {
        float val = acc[m][n][r] + bv;
        if (outBf16) ((u16*)Cv)[(row + r) * (size_t)ldc + n0 + col] = f2bf(val);
        else ((float*)Cv)[(row + r) * (size_t)ldc + n0 + col] = val;
      }
    }
  }
}

// enc_h -> encT[e][b*64+si] bf16
__global__ __launch_bounds__(256) void k_transE(u16* __restrict__ encT,
                                                const float* __restrict__ enc_h) {
  __shared__ u16 ld[64][68];
  int b = blockIdx.x >> 5, et = blockIdx.x & 31;
  int e0 = et * 64;
  int t = threadIdx.x;
  #pragma unroll
  for (int i = 0; i < 4; ++i) {
    int f4 = i * 256 + t;
    int si = f4 >> 4, e4 = (f4 & 15) << 2;
    float4 v = *(const float4*)(enc_h + ((size_t)(b * 64 + si)) * H2_ + e0 + e4);
    ld[si][e4 + 0] = f2bf(v.x); ld[si][e4 + 1] = f2bf(v.y);
    ld[si][e4 + 2] = f2bf(v.z); ld[si][e4 + 3] = f2bf(v.w);
  }
  __syncthreads();
  #pragma unroll
  for (int i = 0; i < 2; ++i) {
    int idx = i * 256 + t;
    int e = idx >> 3, s8 = (idx & 7) << 3;
    short8_t o;
    #pragma unroll
    for (int k = 0; k < 8; ++k) o[k] = (short)ld[s8 + k][e];
    *(short8_t*)(encT + ((size_t)(e0 + e)) * 2048 + b * 64 + s8) = o;
  }
}

// att_Wprev -> wqf frag-major bf16: lin = ((g*32+KB)*4+sub)*16+c, elem j:
// value = W[KB*32+sub*8+j][g*16+c]   (LDS-tiled, coalesced source reads)
__global__ __launch_bounds__(256) void k_packq(u16* __restrict__ wqf,
                                               const float* __restrict__ W) {
  __shared__ float ld[64][33];
  int jt = blockIdx.x & 31, kt = blockIdx.x >> 5;   // 32 x 16
  int c0 = jt * 32, k0 = kt * 64;
  int t = threadIdx.x;
  #pragma unroll
  for (int i = 0; i < 8; ++i) {
    int idx = i * 256 + t; int kr = idx >> 5, jc = idx & 31;
    ld[kr][jc] = W[(size_t)(k0 + kr) * H_ + c0 + jc];
  }
  __syncthreads();
  int u = t;
  int gl = u >> 7, kbl = (u >> 6) & 1, sub = (u >> 4) & 3, c = u & 15;
  int colLoc = gl * 16 + c;
  int gG = jt * 2 + gl, KB = kt * 2 + kbl;
  size_t lin = ((size_t)(gG * 32 + KB) * 4 + sub) * 16 + c;
  short8_t o;
  #pragma unroll
  for (int j = 0; j < 8; ++j) o[j] = (short)f2bf(ld[kbl * 32 + sub * 8 + j][colLoc]);
  *(short8_t*)(wqf + lin * 8) = o;
}

// gate weights -> wgf frag-major (hi in c<8, lo in c>=8), LDS-tiled
__global__ __launch_bounds__(256) void k_packg(
    u16* __restrict__ wgf, const float* __restrict__ Wh, const float* __restrict__ Wc,
    const float* __restrict__ Wh2, const float* __restrict__ Wc2) {
  __shared__ float ld[64][33];
  int sel = blockIdx.x & 1;
  int jt  = (blockIdx.x >> 1) & 31;
  int kt  = blockIdx.x >> 6;          // 0..47
  int k0 = kt * 64, j0 = jt * 32;
  int t = threadIdx.x;
  const float* srcW = (k0 < H_) ? (sel ? Wh2 : Wh) : (sel ? Wc2 : Wc);
  int ldw = sel ? H_ : H2_;
  int koff = (k0 < H_) ? k0 : (k0 - H_);
  #pragma unroll
  for (int i = 0; i < 8; ++i) {
    int idx = i * 256 + t; int kr = idx >> 5, jc = idx & 31;
    ld[kr][jc] = srcW[(size_t)(koff + kr) * ldw + j0 + jc];
  }
  __syncthreads();
  #pragma unroll
  for (int it = 0; it < 2; ++it) {
    int u = it * 256 + t;
    int m = u & 3, sub = (u >> 2) & 3, kbl = (u >> 4) & 1, islo = (u >> 5) & 1, gg = u >> 6;
    int jjLoc = gg * 4 + m;
    int p = 2 * (j0 + jjLoc) + sel;
    int g = p >> 3, cc = p & 7;
    int c = cc + 8 * islo;
    int KB = kt * 2 + kbl;
    size_t lin = ((size_t)(g * 96 + KB) * 4 + sub) * 16 + c;
    short8_t o;
    #pragma unroll
    for (int j = 0; j < 8; ++j) {
      float v = ld[kbl * 32 + sub * 8 + j][jjLoc];
      u16 h = f2bf(v);
      o[j] = (short)(islo ? f2bf(v - bf2f(h)) : h);
    }
    *(short8_t*)(wgf + lin * 8) = o;
  }
}

// out_W half -> wot bf16 [nLocal 16000][k 1024]
__global__ __launch_bounds__(256) void k_wtrans(u16* __restrict__ wot,
                                                const float* __restrict__ W, int nbase) {
  __shared__ u16 ld[64][68];
  int nt = blockIdx.x % 250, kt = blockIdx.x / 250;
  int n0 = nbase + nt * 64, k0 = kt * 64;
  int t = threadIdx.x;
  #pragma unroll
  for (int i = 0; i < 4; ++i) {
    int f4 = i * 256 + t;
    int kr = f4 >> 4, n4 = (f4 & 15) << 2;
    float4 v = *(const float4*)(W + (size_t)(k0 + kr) * V_ + n0 + n4);
    ld[kr][n4 + 0] = f2bf(v.x); ld[kr][n4 + 1] = f2bf(v.y);
    ld[kr][n4 + 2] = f2bf(v.z); ld[kr][n4 + 3] = f2bf(v.w);
  }
  __syncthreads();
  #pragma unroll
  for (int i = 0; i < 2; ++i) {
    int idx = i * 256 + t;
    int n = idx >> 3, k8 = (idx & 7) << 3;
    short8_t o;
    #pragma unroll
    for (int k = 0; k < 8; ++k) o[k] = (short)ld[k8 + k][n];
    *(short8_t*)(wot + ((size_t)(nt * 64 + n)) * H_ + k0 + k8) = o;
  }
}

// final GEMM: dech bf16 [2048][1024] @ wot^T -> C fp32 (per 16000-col half)
__global__ __launch_bounds__(256) void k_gemm2(
    const u16* __restrict__ A, const u16* __restrict__ Bt,
    float* __restrict__ C, const float* __restrict__ bias, int n0g) {
  __shared__ u16 As[128][72];
  __shared__ u16 Bs[128][72];
  int bid = blockIdx.x;
  int lb = (bid & 7) * 250 + (bid >> 3);
  int mtb = lb & 15, ntb = lb >> 4;
  size_t m0 = (size_t)mtb * 128;
  size_t nl0 = (size_t)ntb * 128;
  int t = threadIdx.x, lane = t & 63, wid = t >> 6;
  int wr = (wid >> 1) * 64, wc = (wid & 1) * 64;
  f32x4 acc[4][4] = {};
  for (int k0 = 0; k0 < H_; k0 += 64) {
    #pragma unroll
    for (int i = 0; i < 4; ++i) {
      int idx = i * 256 + t;
      int row = idx >> 3, c8 = (idx & 7) << 3;
      *(short8_t*)&As[row][c8] = *(const short8_t*)(A + (m0 + row) * H_ + k0 + c8);
      *(short8_t*)&Bs[row][c8] = *(const short8_t*)(Bt + (nl0 + row) * H_ + k0 + c8);
    }
    __syncthreads();
    #pragma unroll
    for (int kk = 0; kk < 64; kk += 32) {
      int ko = kk + (lane >> 4) * 8;
      short8_t am[4], bn[4];
      #pragma unroll
      for (int m = 0; m < 4; ++m) am[m] = *(const short8_t*)&As[wr + m * 16 + (lane & 15)][ko];
      #pragma unroll
      for (int n = 0; n < 4; ++n) bn[n] = *(const short8_t*)&Bs[wc + n * 16 + (lane & 15)][ko];
      #pragma unroll
      for (int m = 0; m < 4; ++m)
        #pragma unroll
        for (int n = 0; n < 4; ++n)
          acc[m][n] = __builtin_amdgcn_mfma_f32_16x16x32_bf16(am[m], bn[n], acc[m][n], 0, 0, 0);
    }
    __syncthreads();
  }
  #pragma unroll
  for (int n = 0; n < 4; ++n) {
    int col = n0g + (int)nl0 + wc + n * 16 + (lane & 15);
    float bv = bias[col];
    #pragma unroll
    for (int m = 0; m < 4; ++m) {
      size_t row = m0 + wr + m * 16 + ((lane >> 4) << 2);
      #pragma unroll
      for (int r = 0; r < 4; ++r)
        C[(row + r) * (size_t)V_ + col] = acc[m][n][r] + bv;
    }
  }
}

// ---------------- persistent decoder kernel ----------------

__device__ __forceinline__ void gridbar(int* bar, int target) {
  __syncthreads();
  if (threadIdx.x == 0) {
    int* leaf  = bar;                 // 32 x 16 ints
    int* root  = bar + 512;
    int* epoch = bar + 528;
    int li = (blockIdx.x >> 3) * 16;
    if (__hip_atomic_fetch_add(&leaf[li], 1, __ATOMIC_ACQ_REL, __HIP_MEMORY_SCOPE_AGENT) == 7) {
      __hip_atomic_store(&leaf[li], 0, __ATOMIC_RELAXED, __HIP_MEMORY_SCOPE_AGENT);
      if (__hip_atomic_fetch_add(root, 1, __ATOMIC_ACQ_REL, __HIP_MEMORY_SCOPE_AGENT) == 31) {
        __hip_atomic_store(root, 0, __ATOMIC_RELAXED, __HIP_MEMORY_SCOPE_AGENT);
        __hip_atomic_store(epoch, target, __ATOMIC_RELEASE, __HIP_MEMORY_SCOPE_AGENT);
      }
    }
    while (__hip_atomic_load(epoch, __ATOMIC_RELAXED, __HIP_MEMORY_SCOPE_AGENT) != target)
      __builtin_amdgcn_s_sleep(1);
    __threadfence();
  }
  __syncthreads();
}

#define MFMA16(a, b, c) __builtin_amdgcn_mfma_f32_16x16x32_bf16((a), (b), (c), 0, 0, 0)

__global__ __launch_bounds__(512, 2) void k_mega(
    u16* __restrict__ Xh, u16* __restrict__ Xl,
    float* __restrict__ qf, u16* __restrict__ dech, float* __restrict__ fout,
    const u16* __restrict__ wqf, const u16* __restrict__ wgf,
    const u16* __restrict__ encp, const u16* __restrict__ encT,
    const float* __restrict__ xgr, const float* __restrict__ xg2,
    const float* __restrict__ prev_s, const u16* __restrict__ wlb,
    int* bar) {
  const int t = threadIdx.x, blk = blockIdx.x;
  const int lane = t & 63, wid = t >> 6;
  const int l15 = lane & 15, l4 = lane >> 4;
  const int klo = l4 * 8;
  __shared__ short8_t wg_lds[6144];   // 96KB — gate weights, LDS-resident
  __shared__ f32x4 scr[1024];         // 16KB reduce scratch
  __shared__ float sc[64];
  int ep = 0;

  // LDS-resident gate-weight slice (per block), loaded ONCE
  for (int i = t; i < 6144; i += 512)
    wg_lds[i] = *(const short8_t*)(wgf + ((size_t)blk * 6144 + i) * 8);

  // ---- register-resident operands, loaded ONCE and pinned (KEEPV) ----
  // P1: block gq (<64 active) computes q cols gq*16..+16; wave wid: kb=wid*4+i
  const int gq = blk & 63;
  short8_t wq[4];
  #pragma unroll
  for (int i = 0; i < 4; ++i) {
    wq[i] = *(const short8_t*)(wqf + ((size_t)(gq * 32 + wid * 4 + i) * 64 + lane) * 8);
    KEEPV(wq[i]);
  }
  // P2: b = blk>>3, eg = blk&7 ; wave covers si = wid*8..+8, lane covers j = lane*16..+16
  const int bb = blk >> 3, eg = blk & 7;
  short8_t epv[8][2];
  #pragma unroll
  for (int r = 0; r < 8; ++r) {
    const u16* p = encp + ((size_t)(bb * 64 + wid * 8 + r)) * H_ + lane * 16;
    epv[r][0] = *(const short8_t*)(p);     KEEPV(epv[r][0]);
    epv[r][1] = *(const short8_t*)(p + 8); KEEPV(epv[r][1]);
  }
  short8_t wlv[2];
  wlv[0] = *(const short8_t*)(wlb + lane * 16);     KEEPV(wlv[0]);
  wlv[1] = *(const short8_t*)(wlb + lane * 16 + 8); KEEPV(wlv[1]);
  const int eloc = t >> 1, half = t & 1;
  const int ecol = eg * 256 + eloc;
  short8_t et[4];
  #pragma unroll
  for (int i = 0; i < 4; ++i) {
    et[i] = *(const short8_t*)(encT + (size_t)ecol * 2048 + bb * 64 + half * 32 + i * 8);
    KEEPV(et[i]);
  }

  // finalizer-thread constants + fp32 state in registers (writer == reader)
  const int pc4 = blk * 8 + l15, jcol = pc4 >> 1, isc = pc4 & 1;
  const int rb = wid * 16 + l4 * 4;
  const bool fin = (wid < 2) && (l15 < 8);
  float sreg[4] = {0.f, 0.f, 0.f, 0.f};

  // P0: init X s-part + register state
  {
    int idx = blk * 512 + t;
    if (idx < B_ * H_) {
      int row = idx >> 10, j = idx & 1023;
      float v = prev_s[idx];
      u16 h = f2bf(v);
      Xh[row * K3_ + j] = h;
      Xl[row * K3_ + j] = f2bf(v - bf2f(h));
    }
    if (fin) {
      #pragma unroll
      for (int r = 0; r < 4; ++r) sreg[r] = prev_s[(rb + r) * H_ + jcol];
    }
  }
  gridbar(bar, ++ep);

  for (int ts = 0; ts < T_; ++ts) {
    const int pb = ts & 1;
    u16* XhC = Xh + pb * (B_ * K3_);
    u16* XlC = Xl + pb * (B_ * K3_);
    u16* XhN = Xh + (pb ^ 1) * (B_ * K3_);
    u16* XlN = Xl + (pb ^ 1) * (B_ * K3_);

    // prefetch xg for the gate epilogue (hides under P1/P2)
    float xv[4] = {0.f, 0.f, 0.f, 0.f};
    if (fin) {
      const float* xg = isc ? xg2 : xgr;
      #pragma unroll
      for (int r = 0; r < 4; ++r)
        xv[r] = xg[((size_t)ts * B_ + rb + r) * H_ + jcol];
    }

    // ---- P1: q = s @ Wprev (full-K per block; blocks 0..63) ----
    if (blk < 64) {
      f32x4 aA = {}, aB = {};
      #pragma unroll
      for (int i = 0; i < 4; ++i) {
        int kof = (wid * 4 + i) * 32 + klo;
        short8_t avA = *(const short8_t*)(XhC + l15 * K3_ + kof);
        short8_t avB = *(const short8_t*)(XhC + (l15 + 16) * K3_ + kof);
        aA = MFMA16(avA, wq[i], aA);
        aB = MFMA16(avB, wq[i], aB);
      }
      scr[(wid * 2 + 0) * 64 + lane] = aA;
      scr[(wid * 2 + 1) * 64 + lane] = aB;
      __syncthreads();
      if (wid < 2) {
        f32x4 s = scr[wid * 64 + lane];
        #pragma unroll
        for (int i = 1; i < 8; ++i) s += scr[(i * 2 + wid) * 64 + lane];
        int col = gq * 16 + l15;
        #pragma unroll
        for (int r = 0; r < 4; ++r)
          qf[(size_t)(rb + r) * H_ + col] = s[r];
      }
    }
    gridbar(bar, ++ep);

    // ---- P2: scores (redundant per 8 blocks of same b) + softmax + ctx ----
    {
      float qv[16];
      #pragma unroll
      for (int i = 0; i < 4; ++i) {
        float4 s0 = *(const float4*)(qf + (size_t)bb * H_ + lane * 16 + i * 4);
        qv[i * 4 + 0] = s0.x; qv[i * 4 + 1] = s0.y;
        qv[i * 4 + 2] = s0.z; qv[i * 4 + 3] = s0.w;
      }
      #pragma unroll
      for (int r = 0; r < 8; ++r) {
        float p = 0.f;
        #pragma unroll
        for (int jj = 0; jj < 16; ++jj)
          p += ftanh(bf2f((u16)epv[r][jj >> 3][jj & 7]) + qv[jj]) * bf2f((u16)wlv[jj >> 3][jj & 7]);
        #pragma unroll
        for (int off = 32; off; off >>= 1) p += __shfl_xor(p, off, 64);
        if (lane == 0) sc[wid * 8 + r] = p;
      }
      __syncthreads();
      if (wid == 0) {
        float v = sc[lane];
        float m = v;
        #pragma unroll
        for (int off = 32; off; off >>= 1) m = fmaxf(m, __shfl_xor(m, off, 64));
        float e = __expf(v - m);
        float s = e;
        #pragma unroll
        for (int off = 32; off; off >>= 1) s += __shfl_xor(s, off, 64);
        sc[lane] = e * frcp(s);
      }
      __syncthreads();
      {
        float a = 0.f;
        #pragma unroll
        for (int i = 0; i < 4; ++i)
          #pragma unroll
          for (int j = 0; j < 8; ++j)
            a += sc[half * 32 + i * 8 + j] * bf2f((u16)et[i][j]);
        a += __shfl_xor(a, 1, 64);
        if (half == 0) {
          u16 hh = f2bf(a);
          XhC[bb * K3_ + H_ + ecol] = hh;
          XlC[bb * K3_ + H_ + ecol] = f2bf(a - bf2f(hh));
        }
      }
    }
    gridbar(bar, ++ep);

    // ---- P3: gates ([s|ctx] @ Wcat split-bf16, B from LDS) + state update ----
    {
      f32x4 aA = {}, aB = {};
      #pragma unroll
      for (int i = 0; i < 12; ++i) {
        int kof = (wid * 12 + i) * 32 + klo;
        short8_t hA = *(const short8_t*)(XhC + l15 * K3_ + kof);
        short8_t lA = *(const short8_t*)(XlC + l15 * K3_ + kof);
        short8_t hB = *(const short8_t*)(XhC + (l15 + 16) * K3_ + kof);
        short8_t lB = *(const short8_t*)(XlC + (l15 + 16) * K3_ + kof);
        short8_t bv = wg_lds[(wid * 12 + i) * 64 + lane];
        aA = MFMA16(hA, bv, aA);
        aA = MFMA16(lA, bv, aA);
        aB = MFMA16(hB, bv, aB);
        aB = MFMA16(lB, bv, aB);
      }
      scr[(wid * 2 + 0) * 64 + lane] = aA;
      scr[(wid * 2 + 1) * 64 + lane] = aB;
      __syncthreads();
      if (wid < 2) {
        f32x4 s = scr[wid * 64 + lane];
        #pragma unroll
        for (int i = 1; i < 8; ++i) s += scr[(i * 2 + wid) * 64 + lane];
        float tot[4];
        #pragma unroll
        for (int r = 0; r < 4; ++r) tot[r] = s[r] + __shfl_xor(s[r], 8, 64);
        if (l15 < 8) {
          #pragma unroll
          for (int r = 0; r < 4; ++r) {
            int brow = rb + r;
            float pre = tot[r] + xv[r];
            float mate = __shfl_xor(pre, 1, 64);
            float rpre = isc ? mate : pre;
            float cpre = isc ? pre : mate;
            float rg = fsigm(rpre);
            float cg = ftanh(cpre);
            float sp = sreg[r];
            float sn = sp + rg * (cg - sp);
            sreg[r] = sn;
            if (!isc) {
              u16 hh = f2bf(sn);
              XhN[brow * K3_ + jcol] = hh;
              XlN[brow * K3_ + jcol] = f2bf(sn - bf2f(hh));
              dech[((size_t)brow * T_ + ts) * H_ + jcol] = hh;
              if (ts == T_ - 1) fout[brow * H_ + jcol] = sn;
            }
          }
        }
      }
    }
    gridbar(bar, ++ep);
  }
}

// ---------------- host ----------------

extern "C" void kernel_launch(void* const* d_in, const int* in_sizes, int n_in,
                              void* d_out, int out_size, void* d_ws, size_t ws_size,
                              hipStream_t stream) {
  const float* enc_h    = (const float*)d_in[0];
  const float* prev_s   = (const float*)d_in[1];
  const int*   target   = (const int*)d_in[2];
  const float* embed    = (const float*)d_in[3];
  const float* att_Wenc = (const float*)d_in[4];
  const float* att_benc = (const float*)d_in[5];
  const float* att_Wprev= (const float*)d_in[6];
  const float* att_bprev= (const float*)d_in[7];
  const float* att_wlin = (const float*)d_in[8];
  const float* dc_Wi    = (const float*)d_in[10];
  const float* dc_bi    = (const float*)d_in[11];
  const float* dc_Wh    = (const float*)d_in[12];
  const float* dc_bh    = (const float*)d_in[13];
  const float* dc_Wc    = (const float*)d_in[14];
  const float* dc_bc    = (const float*)d_in[15];
  const float* dc_Wi2   = (const float*)d_in[16];
  const float* dc_bi2   = (const float*)d_in[17];
  const float* dc_Wh2   = (const float*)d_in[18];
  const float* dc_bh2   = (const float*)d_in[19];
  const float* dc_Wc2   = (const float*)d_in[20];
  const float* dc_bc2   = (const float*)d_in[21];
  const float* out_W    = (const float*)d_in[22];
  const float* out_b    = (const float*)d_in[23];

  char* w = (char*)d_ws;
  float* x    = (float*)(w + X_OFF);
  float* xgr  = (float*)(w + XGR_OFF);
  float* xg2  = (float*)(w + XG2_OFF);
  u16*  encp  = (u16*)(w + X_OFF);       // aliases x (after xgr/xg2 gemms)
  u16*  encT  = (u16*)(w + ENCT_OFF);
  u16*  wqf   = (u16*)(w + WQF_OFF);
  u16*  wgf   = (u16*)(w + WGF_OFF);
  u16*  wot   = (u16*)(w + WOT_OFF);     // aliases pool (after mega)
  u16*  dech  = (u16*)(w + DECH_OFF);
  u16*  Xh    = (u16*)(w + XH_OFF);
  u16*  Xl    = (u16*)(w + XL_OFF);
  float* qf   = (float*)(w + QF_OFF);
  float* bas  = (float*)(w + BAS_OFF);
  float* bcr  = (float*)(w + BCR_OFF);
  float* bc2  = (float*)(w + BC2_OFF);
  u16*  wlb   = (u16*)(w + WLB_OFF);
  int*  bar   = (int*)(w + BAR_OFF);
  float* fout = (float*)d_out + (size_t)BT_ * V_;

  hipMemsetAsync(bar, 0, 4096, stream);

  // prologue
  k_gather  <<<BT_, 128, 0, stream>>>(x, embed, target);
  k_biascomb<<<4, 256, 0, stream>>>(bcr, bc2, bas, wlb,
                                    dc_bi, dc_bh, dc_bc, dc_bi2, dc_bh2, dc_bc2,
                                    att_benc, att_bprev, att_wlin);
  k_gemm<<<16 * 8, 256, 0, stream>>>(x, E_, dc_Wi,  H2_, xgr, H_, 0, bcr, 16, 8, E_);
  k_gemm<<<16 * 8, 256, 0, stream>>>(x, E_, dc_Wi2, H_,  xg2, H_, 0, bc2, 16, 8, E_);
  k_gemm<<<16 * 8, 256, 0, stream>>>(enc_h, H2_, att_Wenc, H_, encp, H_, 1, bas, 16, 8, H2_);
  k_transE<<<1024, 256, 0, stream>>>(encT, enc_h);
  k_packq <<<512, 256, 0, stream>>>(wqf, att_Wprev);
  k_packg <<<3072, 256, 0, stream>>>(wgf, dc_Wh, dc_Wc, dc_Wh2, dc_Wc2);

  // the 64-step recurrence in one persistent kernel (weights in LDS/registers)
  k_mega<<<256, 512, 0, stream>>>(Xh, Xl, qf, dech, fout,
                                  wqf, wgf, encp, encT, xgr, xg2,
                                  prev_s, wlb, bar);

  // vocab projection in two halves (wot aliases dead prologue workspace)
  k_wtrans<<<4000, 256, 0, stream>>>(wot, out_W, 0);
  k_gemm2 <<<2000, 256, 0, stream>>>(dech, wot, (float*)d_out, out_b, 0);
  k_wtrans<<<4000, 256, 0, stream>>>(wot, out_W, 16000);
  k_gemm2 <<<2000, 256, 0, stream>>>(dech, wot, (float*)d_out, out_b, 16000);
}

// Round 5
// 3458.554 us; speedup vs baseline: 4.8054x; 1.5937x over previous
//
#include <hip/hip_runtime.h>

// Sizes
#define B_   32
#define S_   64
#define T_   64
#define H_   1024
#define H2_  2048
#define E_   512
#define V_   32000
#define K3_  3072
#define BT_  2048

typedef unsigned short u16;
typedef __attribute__((ext_vector_type(8))) short short8_t;  // 8 x bf16
typedef __attribute__((ext_vector_type(4))) float f32x4;

__device__ __forceinline__ u16 f2bf(float f) {
  unsigned x = __float_as_uint(f);
  unsigned r = (x + 0x7fffu + ((x >> 16) & 1u)) >> 16;  // RNE
  return (u16)r;
}
__device__ __forceinline__ float bf2f(u16 h) {
  return __uint_as_float(((unsigned)h) << 16);
}
__device__ __forceinline__ float frcp(float x) { return __builtin_amdgcn_rcpf(x); }
__device__ __forceinline__ float ftanh(float x) {
  float e = __expf(2.f * x);
  return 1.f - 2.f * frcp(e + 1.f);
}
__device__ __forceinline__ float fsigm(float x) {
  return frcp(1.f + __expf(-x));
}

// pin a loaded value in VGPRs: opaque asm result cannot be rematerialized
#define KEEPV(x) asm volatile("" : "+v"(x))

// write-through to the coherent point (LLC) — visible cross-XCD, no fence
__device__ __forceinline__ void st_u16(u16* p, u16 v) {
  __hip_atomic_store(p, v, __ATOMIC_RELAXED, __HIP_MEMORY_SCOPE_AGENT);
}
__device__ __forceinline__ void st_f32(float* p, float v) {
  __hip_atomic_store(p, v, __ATOMIC_RELAXED, __HIP_MEMORY_SCOPE_AGENT);
}

// ---------------- workspace layout (bytes) ----------------
#define MB_ (1ull << 20)
#define KB_ (1ull << 10)
#define X_OFF    (0)              // 4MB; encp aliases after xgr/xg2 gemms
#define XGR_OFF  (4*MB_)          // 8MB
#define XG2_OFF  (12*MB_)         // 8MB
#define ENCT_OFF (20*MB_)         // 8MB (pre-loop only)
#define QFV_OFF  (20*MB_)         // qf versions t=0..63 x 128KB (aliases encT)
#define WQF_OFF  (28*MB_)         // 2MB (pre-loop only)
#define WGF_OFF  (30*MB_)         // 24MB (pre-loop only)
#define XSV_OFF  (28*MB_)         // Xs versions t=1..64 x 128KB -> [28,36)
#define XCV_OFF  (36*MB_)         // Xc versions t=0..63 x 256KB -> [36,52)
#define WOT_OFF  (0)              // 32MB (after mega only)
#define DECH_OFF (54*MB_)         // 4MB
#define XS0_OFF  (58*MB_)         // 128KB (Xs version 0, written pre-barrier)
#define BAS_OFF  (58*MB_ + 128*KB_)   // 4KB
#define BCR_OFF  (58*MB_ + 132*KB_)   // 4KB
#define BC2_OFF  (58*MB_ + 136*KB_)   // 4KB
#define WLB_OFF  (58*MB_ + 140*KB_)   // 2KB
#define BAR_OFF  (58*MB_ + 144*KB_)   // 4KB

// version-buffer address helpers
__device__ __forceinline__ u16* xs_hi(char* w, int t) {
  return (u16*)(t == 0 ? (w + XS0_OFF) : (w + XSV_OFF + (size_t)(t - 1) * 131072));
}
__device__ __forceinline__ u16* xc_hi(char* w, int t) {
  return (u16*)(w + XCV_OFF + (size_t)t * 262144);
}
__device__ __forceinline__ float* qf_v(char* w, int t) {
  return (float*)(w + QFV_OFF + (size_t)t * 131072);
}

// ---------------- prologue kernels ----------------

__global__ void k_gather(float* __restrict__ x, const float* __restrict__ embed,
                         const int* __restrict__ tgt) {
  int bid = blockIdx.x;              // t*B + b
  int t = bid >> 5, b = bid & 31;
  int row = tgt[b * T_ + t];
  const float4* src = (const float4*)(embed + (size_t)row * E_);
  float4* dst = (float4*)(x + (size_t)bid * E_);
  dst[threadIdx.x] = src[threadIdx.x];
}

__global__ void k_biascomb(float* bcr, float* bc2o, float* bas, u16* wlb,
                           const float* bi, const float* bh, const float* bc,
                           const float* bi2, const float* bh2, const float* bc2i,
                           const float* benc, const float* bprev, const float* wlin) {
  int j = blockIdx.x * 256 + threadIdx.x;
  if (j < H_) {
    bcr[j]  = bi[j]  + bh[j]  + bc[j];
    bc2o[j] = bi2[j] + bh2[j] + bc2i[j];
    bas[j]  = benc[j] + bprev[j];
    wlb[j]  = f2bf(wlin[j]);
  }
}

// generic 128x128 bf16-MFMA GEMM (fp32 in, fp32/bf16 out) — prologue only
__global__ __launch_bounds__(256) void k_gemm(
    const float* __restrict__ A, int lda,
    const float* __restrict__ Bm, int ldb,
    void* __restrict__ Cv, int ldc, int outBf16,
    const float* __restrict__ bias,
    int mtiles, int ntiles, int K) {
  __shared__ u16 As[128][72];
  __shared__ u16 Bs[128][72];
  int nwg = mtiles * ntiles;
  int bid = blockIdx.x;
  int cpx = nwg >> 3;
  int lb = (bid & 7) * cpx + (bid >> 3);
  int ntb = lb / mtiles, mtb = lb - ntb * mtiles;
  size_t m0 = (size_t)mtb * 128, n0 = (size_t)ntb * 128;
  int t = threadIdx.x, lane = t & 63, wid = t >> 6;
  int wr = (wid >> 1) * 64, wc = (wid & 1) * 64;
  f32x4 acc[4][4] = {};
  for (int k0 = 0; k0 < K; k0 += 64) {
    #pragma unroll
    for (int i = 0; i < 8; ++i) {
      int f4 = i * 256 + t;
      int row = f4 >> 4, c4 = (f4 & 15) << 2;
      float4 v = *(const float4*)(A + (m0 + row) * (size_t)lda + k0 + c4);
      ushort4 u; u.x = f2bf(v.x); u.y = f2bf(v.y); u.z = f2bf(v.z); u.w = f2bf(v.w);
      *(ushort4*)&As[row][c4] = u;
    }
    #pragma unroll
    for (int i = 0; i < 8; ++i) {
      int f4 = i * 256 + t;
      int kr = f4 >> 5, c4 = (f4 & 31) << 2;
      float4 v = *(const float4*)(Bm + (size_t)(k0 + kr) * ldb + n0 + c4);
      Bs[c4 + 0][kr] = f2bf(v.x);
      Bs[c4 + 1][kr] = f2bf(v.y);
      Bs[c4 + 2][kr] = f2bf(v.z);
      Bs[c4 + 3][kr] = f2bf(v.w);
    }
    __syncthreads();
    #pragma unroll
    for (int kk = 0; kk < 64; kk += 32) {
      int ko = kk + (lane >> 4) * 8;
      short8_t am[4], bn[4];
      #pragma unroll
      for (int m = 0; m < 4; ++m) am[m] = *(const short8_t*)&As[wr + m * 16 + (lane & 15)][ko];
      #pragma unroll
      for (int n = 0; n < 4; ++n) bn[n] = *(const short8_t*)&Bs[wc + n * 16 + (lane & 15)][ko];
      #pragma unroll
      for (int m = 0; m < 4; ++m)
        #pragma unroll
        for (int n = 0; n < 4; ++n)
          acc[m][n] = __builtin_amdgcn_mfma_f32_16x16x32_bf16(am[m], bn[n], acc[m][n], 0, 0, 0);
    }
    __syncthreads();
  }
  #pragma unroll
  for (int n = 0; n < 4; ++n) {
    int col = wc + n * 16 + (lane & 15);
    float bv = bias ? bias[n0 + col] : 0.f;
    #pragma unroll
    for (int m = 0; m < 4; ++m) {
      size_t row = m0 + wr + m * 16 + ((lane >> 4) << 2);
      #pragma unroll
      for (int r = 0; r < 4; ++r) {
        float val = acc[m][n][r] + bv;
        if (outBf16) ((u16*)Cv)[(row + r) * (size_t)ldc + n0 + col] = f2bf(val);
        else ((float*)Cv)[(row + r) * (size_t)ldc + n0 + col] = val;
      }
    }
  }
}

// enc_h -> encT[e][b*64+si] bf16
__global__ __launch_bounds__(256) void k_transE(u16* __restrict__ encT,
                                                const float* __restrict__ enc_h) {
  __shared__ u16 ld[64][68];
  int b = blockIdx.x >> 5, et = blockIdx.x & 31;
  int e0 = et * 64;
  int t = threadIdx.x;
  #pragma unroll
  for (int i = 0; i < 4; ++i) {
    int f4 = i * 256 + t;
    int si = f4 >> 4, e4 = (f4 & 15) << 2;
    float4 v = *(const float4*)(enc_h + ((size_t)(b * 64 + si)) * H2_ + e0 + e4);
    ld[si][e4 + 0] = f2bf(v.x); ld[si][e4 + 1] = f2bf(v.y);
    ld[si][e4 + 2] = f2bf(v.z); ld[si][e4 + 3] = f2bf(v.w);
  }
  __syncthreads();
  #pragma unroll
  for (int i = 0; i < 2; ++i) {
    int idx = i * 256 + t;
    int e = idx >> 3, s8 = (idx & 7) << 3;
    short8_t o;
    #pragma unroll
    for (int k = 0; k < 8; ++k) o[k] = (short)ld[s8 + k][e];
    *(short8_t*)(encT + ((size_t)(e0 + e)) * 2048 + b * 64 + s8) = o;
  }
}

// att_Wprev -> wqf frag-major bf16 (LDS-tiled, coalesced source reads)
__global__ __launch_bounds__(256) void k_packq(u16* __restrict__ wqf,
                                               const float* __restrict__ W) {
  __shared__ float ld[64][33];
  int jt = blockIdx.x & 31, kt = blockIdx.x >> 5;   // 32 x 16
  int c0 = jt * 32, k0 = kt * 64;
  int t = threadIdx.x;
  #pragma unroll
  for (int i = 0; i < 8; ++i) {
    int idx = i * 256 + t; int kr = idx >> 5, jc = idx & 31;
    ld[kr][jc] = W[(size_t)(k0 + kr) * H_ + c0 + jc];
  }
  __syncthreads();
  int u = t;
  int gl = u >> 7, kbl = (u >> 6) & 1, sub = (u >> 4) & 3, c = u & 15;
  int colLoc = gl * 16 + c;
  int gG = jt * 2 + gl, KB = kt * 2 + kbl;
  size_t lin = ((size_t)(gG * 32 + KB) * 4 + sub) * 16 + c;
  short8_t o;
  #pragma unroll
  for (int j = 0; j < 8; ++j) o[j] = (short)f2bf(ld[kbl * 32 + sub * 8 + j][colLoc]);
  *(short8_t*)(wqf + lin * 8) = o;
}

// gate weights -> wgf frag-major (hi in c<8, lo in c>=8), LDS-tiled
__global__ __launch_bounds__(256) void k_packg(
    u16* __restrict__ wgf, const float* __restrict__ Wh, const float* __restrict__ Wc,
    const float* __restrict__ Wh2, const float* __restrict__ Wc2) {
  __shared__ float ld[64][33];
  int sel = blockIdx.x & 1;
  int jt  = (blockIdx.x >> 1) & 31;
  int kt  = blockIdx.x >> 6;          // 0..47
  int k0 = kt * 64, j0 = jt * 32;
  int t = threadIdx.x;
  const float* srcW = (k0 < H_) ? (sel ? Wh2 : Wh) : (sel ? Wc2 : Wc);
  int ldw = sel ? H_ : H2_;
  int koff = (k0 < H_) ? k0 : (k0 - H_);
  #pragma unroll
  for (int i = 0; i < 8; ++i) {
    int idx = i * 256 + t; int kr = idx >> 5, jc = idx & 31;
    ld[kr][jc] = srcW[(size_t)(koff + kr) * ldw + j0 + jc];
  }
  __syncthreads();
  #pragma unroll
  for (int it = 0; it < 2; ++it) {
    int u = it * 256 + t;
    int m = u & 3, sub = (u >> 2) & 3, kbl = (u >> 4) & 1, islo = (u >> 5) & 1, gg = u >> 6;
    int jjLoc = gg * 4 + m;
    int p = 2 * (j0 + jjLoc) + sel;
    int g = p >> 3, cc = p & 7;
    int c = cc + 8 * islo;
    int KB = kt * 2 + kbl;
    size_t lin = ((size_t)(g * 96 + KB) * 4 + sub) * 16 + c;
    short8_t o;
    #pragma unroll
    for (int j = 0; j < 8; ++j) {
      float v = ld[kbl * 32 + sub * 8 + j][jjLoc];
      u16 h = f2bf(v);
      o[j] = (short)(islo ? f2bf(v - bf2f(h)) : h);
    }
    *(short8_t*)(wgf + lin * 8) = o;
  }
}

// out_W half -> wot bf16 [nLocal 16000][k 1024]
__global__ __launch_bounds__(256) void k_wtrans(u16* __restrict__ wot,
                                                const float* __restrict__ W, int nbase) {
  __shared__ u16 ld[64][68];
  int nt = blockIdx.x % 250, kt = blockIdx.x / 250;
  int n0 = nbase + nt * 64, k0 = kt * 64;
  int t = threadIdx.x;
  #pragma unroll
  for (int i = 0; i < 4; ++i) {
    int f4 = i * 256 + t;
    int kr = f4 >> 4, n4 = (f4 & 15) << 2;
    float4 v = *(const float4*)(W + (size_t)(k0 + kr) * V_ + n0 + n4);
    ld[kr][n4 + 0] = f2bf(v.x); ld[kr][n4 + 1] = f2bf(v.y);
    ld[kr][n4 + 2] = f2bf(v.z); ld[kr][n4 + 3] = f2bf(v.w);
  }
  __syncthreads();
  #pragma unroll
  for (int i = 0; i < 2; ++i) {
    int idx = i * 256 + t;
    int n = idx >> 3, k8 = (idx & 7) << 3;
    short8_t o;
    #pragma unroll
    for (int k = 0; k < 8; ++k) o[k] = (short)ld[k8 + k][n];
    *(short8_t*)(wot + ((size_t)(nt * 64 + n)) * H_ + k0 + k8) = o;
  }
}

// final GEMM: dech bf16 [2048][1024] @ wot^T -> C fp32 (per 16000-col half)
__global__ __launch_bounds__(256) void k_gemm2(
    const u16* __restrict__ A, const u16* __restrict__ Bt,
    float* __restrict__ C, const float* __restrict__ bias, int n0g) {
  __shared__ u16 As[128][72];
  __shared__ u16 Bs[128][72];
  int bid = blockIdx.x;
  int lb = (bid & 7) * 250 + (bid >> 3);
  int mtb = lb & 15, ntb = lb >> 4;
  size_t m0 = (size_t)mtb * 128;
  size_t nl0 = (size_t)ntb * 128;
  int t = threadIdx.x, lane = t & 63, wid = t >> 6;
  int wr = (wid >> 1) * 64, wc = (wid & 1) * 64;
  f32x4 acc[4][4] = {};
  for (int k0 = 0; k0 < H_; k0 += 64) {
    #pragma unroll
    for (int i = 0; i < 4; ++i) {
      int idx = i * 256 + t;
      int row = idx >> 3, c8 = (idx & 7) << 3;
      *(short8_t*)&As[row][c8] = *(const short8_t*)(A + (m0 + row) * H_ + k0 + c8);
      *(short8_t*)&Bs[row][c8] = *(const short8_t*)(Bt + (nl0 + row) * H_ + k0 + c8);
    }
    __syncthreads();
    #pragma unroll
    for (int kk = 0; kk < 64; kk += 32) {
      int ko = kk + (lane >> 4) * 8;
      short8_t am[4], bn[4];
      #pragma unroll
      for (int m = 0; m < 4; ++m) am[m] = *(const short8_t*)&As[wr + m * 16 + (lane & 15)][ko];
      #pragma unroll
      for (int n = 0; n < 4; ++n) bn[n] = *(const short8_t*)&Bs[wc + n * 16 + (lane & 15)][ko];
      #pragma unroll
      for (int m = 0; m < 4; ++m)
        #pragma unroll
        for (int n = 0; n < 4; ++n)
          acc[m][n] = __builtin_amdgcn_mfma_f32_16x16x32_bf16(am[m], bn[n], acc[m][n], 0, 0, 0);
    }
    __syncthreads();
  }
  #pragma unroll
  for (int n = 0; n < 4; ++n) {
    int col = n0g + (int)nl0 + wc + n * 16 + (lane & 15);
    float bv = bias[col];
    #pragma unroll
    for (int m = 0; m < 4; ++m) {
      size_t row = m0 + wr + m * 16 + ((lane >> 4) << 2);
      #pragma unroll
      for (int r = 0; r < 4; ++r)
        C[(row + r) * (size_t)V_ + col] = acc[m][n][r] + bv;
    }
  }
}

// ---------------- persistent decoder kernel ----------------

// relaxed barrier: no cache maintenance. Correctness: all communicated data is
// (a) written via agent-scope atomic stores (write-through to LLC) drained by
// the explicit vmcnt(0) before arrival, and (b) read via version-fresh
// addresses never previously cached on the reader's XCD.
__device__ __forceinline__ void gridbar(int* bar, int target) {
  asm volatile("s_waitcnt vmcnt(0)" ::: "memory");
  __syncthreads();
  if (threadIdx.x == 0) {
    int* leaf  = bar;                 // 32 x 16 ints
    int* root  = bar + 512;
    int* epoch = bar + 528;
    int li = (blockIdx.x >> 3) * 16;
    if (__hip_atomic_fetch_add(&leaf[li], 1, __ATOMIC_RELAXED, __HIP_MEMORY_SCOPE_AGENT) == 7) {
      __hip_atomic_store(&leaf[li], 0, __ATOMIC_RELAXED, __HIP_MEMORY_SCOPE_AGENT);
      if (__hip_atomic_fetch_add(root, 1, __ATOMIC_RELAXED, __HIP_MEMORY_SCOPE_AGENT) == 31) {
        __hip_atomic_store(root, 0, __ATOMIC_RELAXED, __HIP_MEMORY_SCOPE_AGENT);
        __hip_atomic_store(epoch, target, __ATOMIC_RELAXED, __HIP_MEMORY_SCOPE_AGENT);
      }
    }
    while (__hip_atomic_load(epoch, __ATOMIC_RELAXED, __HIP_MEMORY_SCOPE_AGENT) != target)
      __builtin_amdgcn_s_sleep(1);
  }
  __syncthreads();
}

#define MFMA16(a, b, c) __builtin_amdgcn_mfma_f32_16x16x32_bf16((a), (b), (c), 0, 0, 0)

__global__ __launch_bounds__(512, 2) void k_mega(
    char* w, u16* __restrict__ dech, float* __restrict__ fout,
    const u16* __restrict__ wqf, const u16* __restrict__ wgf,
    const u16* __restrict__ encp, const u16* __restrict__ encT,
    const float* __restrict__ xgr, const float* __restrict__ xg2,
    const float* __restrict__ prev_s, const u16* __restrict__ wlb,
    int* bar) {
  const int t = threadIdx.x, blk = blockIdx.x;
  const int lane = t & 63, wid = t >> 6;
  const int l15 = lane & 15, l4 = lane >> 4;
  const int klo = l4 * 8;
  __shared__ short8_t wg_lds[6144];   // 96KB — gate weights, LDS-resident
  __shared__ f32x4 scr[1024];         // 16KB reduce scratch
  __shared__ float sc[64];
  int ep = 0;

  // LDS-resident gate-weight slice (per block), loaded ONCE (pre-loop only)
  for (int i = t; i < 6144; i += 512)
    wg_lds[i] = *(const short8_t*)(wgf + ((size_t)blk * 6144 + i) * 8);

  // ---- register-resident operands, loaded ONCE and pinned (KEEPV) ----
  const int gq = blk & 63;
  short8_t wq[4];
  #pragma unroll
  for (int i = 0; i < 4; ++i) {
    wq[i] = *(const short8_t*)(wqf + ((size_t)(gq * 32 + wid * 4 + i) * 64 + lane) * 8);
    KEEPV(wq[i]);
  }
  const int bb = blk >> 3, eg = blk & 7;
  short8_t epv[8][2];
  #pragma unroll
  for (int r = 0; r < 8; ++r) {
    const u16* p = encp + ((size_t)(bb * 64 + wid * 8 + r)) * H_ + lane * 16;
    epv[r][0] = *(const short8_t*)(p);     KEEPV(epv[r][0]);
    epv[r][1] = *(const short8_t*)(p + 8); KEEPV(epv[r][1]);
  }
  short8_t wlv[2];
  wlv[0] = *(const short8_t*)(wlb + lane * 16);     KEEPV(wlv[0]);
  wlv[1] = *(const short8_t*)(wlb + lane * 16 + 8); KEEPV(wlv[1]);
  const int eloc = t >> 1, half = t & 1;
  const int ecol = eg * 256 + eloc;
  short8_t et[4];
  #pragma unroll
  for (int i = 0; i < 4; ++i) {
    et[i] = *(const short8_t*)(encT + (size_t)ecol * 2048 + bb * 64 + half * 32 + i * 8);
    KEEPV(et[i]);
  }

  // finalizer-thread constants + fp32 state in registers (writer == reader)
  const int pc4 = blk * 8 + l15, jcol = pc4 >> 1, isc = pc4 & 1;
  const int rb = wid * 16 + l4 * 4;
  const bool fin = (wid < 2) && (l15 < 8);
  float sreg[4] = {0.f, 0.f, 0.f, 0.f};

  // P0: init Xs[0] + register state
  {
    int idx = blk * 512 + t;
    u16* xs0h = xs_hi(w, 0);
    u16* xs0l = xs0h + B_ * H_;
    if (idx < B_ * H_) {
      float v = prev_s[idx];
      u16 h = f2bf(v);
      st_u16(&xs0h[idx], h);
      st_u16(&xs0l[idx], f2bf(v - bf2f(h)));
    }
    if (fin) {
      #pragma unroll
      for (int r = 0; r < 4; ++r) sreg[r] = prev_s[(rb + r) * H_ + jcol];
    }
  }
  gridbar(bar, ++ep);

  for (int ts = 0; ts < T_; ++ts) {
    const u16* xsh = xs_hi(w, ts);
    const u16* xsl = xsh + B_ * H_;
    u16* xch = xc_hi(w, ts);
    u16* xcl = xch + B_ * H2_;
    float* qfv = qf_v(w, ts);

    // prefetch xg for the gate epilogue (hides under P1/P2)
    float xv[4] = {0.f, 0.f, 0.f, 0.f};
    if (fin) {
      const float* xg = isc ? xg2 : xgr;
      #pragma unroll
      for (int r = 0; r < 4; ++r)
        xv[r] = xg[((size_t)ts * B_ + rb + r) * H_ + jcol];
    }

    // ---- P1: q = s @ Wprev (full-K per block; blocks 0..63) ----
    if (blk < 64) {
      f32x4 aA = {}, aB = {};
      #pragma unroll
      for (int i = 0; i < 4; ++i) {
        int kof = (wid * 4 + i) * 32 + klo;
        short8_t avA = *(const short8_t*)(xsh + l15 * H_ + kof);
        short8_t avB = *(const short8_t*)(xsh + (l15 + 16) * H_ + kof);
        aA = MFMA16(avA, wq[i], aA);
        aB = MFMA16(avB, wq[i], aB);
      }
      scr[(wid * 2 + 0) * 64 + lane] = aA;
      scr[(wid * 2 + 1) * 64 + lane] = aB;
      __syncthreads();
      if (wid < 2) {
        f32x4 s = scr[wid * 64 + lane];
        #pragma unroll
        for (int i = 1; i < 8; ++i) s += scr[(i * 2 + wid) * 64 + lane];
        int col = gq * 16 + l15;
        #pragma unroll
        for (int r = 0; r < 4; ++r)
          st_f32(&qfv[(size_t)(rb + r) * H_ + col], s[r]);
      }
    }
    gridbar(bar, ++ep);

    // ---- P2: scores (8-way redundant per b) + softmax + ctx ----
    {
      float qv[16];
      #pragma unroll
      for (int i = 0; i < 4; ++i) {
        float4 s0 = *(const float4*)(qfv + (size_t)bb * H_ + lane * 16 + i * 4);
        qv[i * 4 + 0] = s0.x; qv[i * 4 + 1] = s0.y;
        qv[i * 4 + 2] = s0.z; qv[i * 4 + 3] = s0.w;
      }
      #pragma unroll
      for (int r = 0; r < 8; ++r) {
        float p = 0.f;
        #pragma unroll
        for (int jj = 0; jj < 16; ++jj)
          p += ftanh(bf2f((u16)epv[r][jj >> 3][jj & 7]) + qv[jj]) * bf2f((u16)wlv[jj >> 3][jj & 7]);
        #pragma unroll
        for (int off = 32; off; off >>= 1) p += __shfl_xor(p, off, 64);
        if (lane == 0) sc[wid * 8 + r] = p;
      }
      __syncthreads();
      if (wid == 0) {
        float v = sc[lane];
        float m = v;
        #pragma unroll
        for (int off = 32; off; off >>= 1) m = fmaxf(m, __shfl_xor(m, off, 64));
        float e = __expf(v - m);
        float s = e;
        #pragma unroll
        for (int off = 32; off; off >>= 1) s += __shfl_xor(s, off, 64);
        sc[lane] = e * frcp(s);
      }
      __syncthreads();
      {
        float a = 0.f;
        #pragma unroll
        for (int i = 0; i < 4; ++i)
          #pragma unroll
          for (int j = 0; j < 8; ++j)
            a += sc[half * 32 + i * 8 + j] * bf2f((u16)et[i][j]);
        a += __shfl_xor(a, 1, 64);
        if (half == 0) {
          u16 hh = f2bf(a);
          st_u16(&xch[bb * H2_ + ecol], hh);
          st_u16(&xcl[bb * H2_ + ecol], f2bf(a - bf2f(hh)));
        }
      }
    }
    gridbar(bar, ++ep);

    // ---- P3: gates ([s|ctx] @ Wcat split-bf16, B from LDS) + state update ----
    {
      f32x4 aA = {}, aB = {};
      #pragma unroll
      for (int i = 0; i < 12; ++i) {
        int kb = wid * 12 + i;
        int k = kb * 32 + klo;
        const u16 *ah, *al; int rs;
        if (kb < 32) { ah = xsh + l15 * H_ + k;          al = xsl + l15 * H_ + k;          rs = H_;  }
        else         { ah = xch + l15 * H2_ + (k - H_);  al = xcl + l15 * H2_ + (k - H_);  rs = H2_; }
        short8_t hA = *(const short8_t*)ah;
        short8_t lA = *(const short8_t*)al;
        short8_t hB = *(const short8_t*)(ah + 16 * rs);
        short8_t lB = *(const short8_t*)(al + 16 * rs);
        short8_t bv = wg_lds[kb * 64 + lane];
        aA = MFMA16(hA, bv, aA);
        aA = MFMA16(lA, bv, aA);
        aB = MFMA16(hB, bv, aB);
        aB = MFMA16(lB, bv, aB);
      }
      scr[(wid * 2 + 0) * 64 + lane] = aA;
      scr[(wid * 2 + 1) * 64 + lane] = aB;
      __syncthreads();
      if (wid < 2) {
        f32x4 s = scr[wid * 64 + lane];
        #pragma unroll
        for (int i = 1; i < 8; ++i) s += scr[(i * 2 + wid) * 64 + lane];
        float tot[4];
        #pragma unroll
        for (int r = 0; r < 4; ++r) tot[r] = s[r] + __shfl_xor(s[r], 8, 64);
        if (l15 < 8) {
          u16* nsh = xs_hi(w, ts + 1);
          u16* nsl = nsh + B_ * H_;
          #pragma unroll
          for (int r = 0; r < 4; ++r) {
            int brow = rb + r;
            float pre = tot[r] + xv[r];
            float mate = __shfl_xor(pre, 1, 64);
            float rpre = isc ? mate : pre;
            float cpre = isc ? pre : mate;
            float rg = fsigm(rpre);
            float cg = ftanh(cpre);
            float sp = sreg[r];
            float sn = sp + rg * (cg - sp);
            sreg[r] = sn;
            if (!isc) {
              u16 hh = f2bf(sn);
              st_u16(&nsh[brow * H_ + jcol], hh);
              st_u16(&nsl[brow * H_ + jcol], f2bf(sn - bf2f(hh)));
              dech[((size_t)brow * T_ + ts) * H_ + jcol] = hh;
              if (ts == T_ - 1) fout[brow * H_ + jcol] = sn;
            }
          }
        }
      }
    }
    gridbar(bar, ++ep);
  }
}

// ---------------- host ----------------

extern "C" void kernel_launch(void* const* d_in, const int* in_sizes, int n_in,
                              void* d_out, int out_size, void* d_ws, size_t ws_size,
                              hipStream_t stream) {
  const float* enc_h    = (const float*)d_in[0];
  const float* prev_s   = (const float*)d_in[1];
  const int*   target   = (const int*)d_in[2];
  const float* embed    = (const float*)d_in[3];
  const float* att_Wenc = (const float*)d_in[4];
  const float* att_benc = (const float*)d_in[5];
  const float* att_Wprev= (const float*)d_in[6];
  const float* att_bprev= (const float*)d_in[7];
  const float* att_wlin = (const float*)d_in[8];
  const float* dc_Wi    = (const float*)d_in[10];
  const float* dc_bi    = (const float*)d_in[11];
  const float* dc_Wh    = (const float*)d_in[12];
  const float* dc_bh    = (const float*)d_in[13];
  const float* dc_Wc    = (const float*)d_in[14];
  const float* dc_bc    = (const float*)d_in[15];
  const float* dc_Wi2   = (const float*)d_in[16];
  const float* dc_bi2   = (const float*)d_in[17];
  const float* dc_Wh2   = (const float*)d_in[18];
  const float* dc_bh2   = (const float*)d_in[19];
  const float* dc_Wc2   = (const float*)d_in[20];
  const float* dc_bc2   = (const float*)d_in[21];
  const float* out_W    = (const float*)d_in[22];
  const float* out_b    = (const float*)d_in[23];

  char* w = (char*)d_ws;
  float* x    = (float*)(w + X_OFF);
  float* xgr  = (float*)(w + XGR_OFF);
  float* xg2  = (float*)(w + XG2_OFF);
  u16*  encp  = (u16*)(w + X_OFF);       // aliases x (after xgr/xg2 gemms)
  u16*  encT  = (u16*)(w + ENCT_OFF);
  u16*  wqf   = (u16*)(w + WQF_OFF);
  u16*  wgf   = (u16*)(w + WGF_OFF);
  u16*  wot   = (u16*)(w + WOT_OFF);     // aliases pool (after mega)
  u16*  dech  = (u16*)(w + DECH_OFF);
  float* bas  = (float*)(w + BAS_OFF);
  float* bcr  = (float*)(w + BCR_OFF);
  float* bc2  = (float*)(w + BC2_OFF);
  u16*  wlb   = (u16*)(w + WLB_OFF);
  int*  bar   = (int*)(w + BAR_OFF);
  float* fout = (float*)d_out + (size_t)BT_ * V_;

  hipMemsetAsync(bar, 0, 4096, stream);

  // prologue
  k_gather  <<<BT_, 128, 0, stream>>>(x, embed, target);
  k_biascomb<<<4, 256, 0, stream>>>(bcr, bc2, bas, wlb,
                                    dc_bi, dc_bh, dc_bc, dc_bi2, dc_bh2, dc_bc2,
                                    att_benc, att_bprev, att_wlin);
  k_gemm<<<16 * 8, 256, 0, stream>>>(x, E_, dc_Wi,  H2_, xgr, H_, 0, bcr, 16, 8, E_);
  k_gemm<<<16 * 8, 256, 0, stream>>>(x, E_, dc_Wi2, H_,  xg2, H_, 0, bc2, 16, 8, E_);
  k_gemm<<<16 * 8, 256, 0, stream>>>(enc_h, H2_, att_Wenc, H_, encp, H_, 1, bas, 16, 8, H2_);
  k_transE<<<1024, 256, 0, stream>>>(encT, enc_h);
  k_packq <<<512, 256, 0, stream>>>(wqf, att_Wprev);
  k_packg <<<3072, 256, 0, stream>>>(wgf, dc_Wh, dc_Wc, dc_Wh2, dc_Wc2);

  // the 64-step recurrence: versioned buffers + relaxed barriers (no L2 inv)
  k_mega<<<256, 512, 0, stream>>>(w, dech, fout,
                                  wqf, wgf, encp, encT, xgr, xg2,
                                  prev_s, wlb, bar);

  // vocab projection in two halves (wot aliases dead prologue workspace)
  k_wtrans<<<4000, 256, 0, stream>>>(wot, out_W, 0);
  k_gemm2 <<<2000, 256, 0, stream>>>(dech, wot, (float*)d_out, out_b, 0);
  k_wtrans<<<4000, 256, 0, stream>>>(wot, out_W, 16000);
  k_gemm2 <<<2000, 256, 0, stream>>>(dech, wot, (float*)d_out, out_b, 16000);
}